// Round 1
// baseline (3103.883 us; speedup 1.0000x reference)
//
#include <hip/hip_runtime.h>
#include <math.h>

#define N_USER 50000
#define N_ITEM 50000
#define NTOT   100000
#define D      128
#define BATCH_ 4096
#define NEG_SLOPE 0.2f
#define EPS_ 1e-12f

// ---------------------------------------------------------------- ego0 assembly
__global__ void assemble_ego0(const float* __restrict__ user_emb,
                              const float* __restrict__ item_emb1,
                              const float* __restrict__ item_emb2,
                              const float* __restrict__ feature,
                              float* __restrict__ ego0) {
    int t = blockIdx.x * blockDim.x + threadIdx.x;   // float4 slot index
    const int total = NTOT * (D / 4);
    if (t >= total) return;
    int row = t >> 5;          // 32 float4 per row
    int q   = t & 31;
    int d0  = q * 4;
    const float* src;
    if (d0 < 64) {
        src = (row < N_USER) ? user_emb  + (size_t)row * 64 + d0
                             : item_emb1 + (size_t)(row - N_USER) * 64 + d0;
    } else {
        src = (row < N_USER) ? feature   + (size_t)row * 64 + (d0 - 64)
                             : item_emb2 + (size_t)(row - N_USER) * 64 + (d0 - 64);
    }
    float4 v = *(const float4*)src;
    *(float4*)(ego0 + (size_t)row * D + d0) = v;
}

// ---------------------------------------------------------------- SpMM (atomic scatter)
__global__ void spmm_atomic(const int* __restrict__ rows,
                            const int* __restrict__ cols,
                            const float* __restrict__ vals,
                            const float* __restrict__ w3,
                            const float* __restrict__ X,
                            float* __restrict__ side,
                            int nnz) {
    const float w0 = w3[0], w1 = w3[1], w2 = w3[2];
    int lane   = threadIdx.x & 63;
    int gwave  = (blockIdx.x * blockDim.x + threadIdx.x) >> 6;
    int nwaves = (gridDim.x * blockDim.x) >> 6;
    for (int e = gwave; e < nnz; e += nwaves) {
        int   r = rows[e];
        int   c = cols[e];
        float v = vals[e];
        float v2   = v * v;
        float comb = w0 * v + w1 * v2 + w2 * v2 * v2 * v2;
        const float* xp = X    + (size_t)c * D;
        float*       sp = side + (size_t)r * D;
        atomicAdd(sp + lane,      comb * xp[lane]);
        atomicAdd(sp + lane + 64, comb * xp[lane + 64]);
    }
}

// ---------------------------------------------------------------- fused layer GEMM
// ego_out = leaky_relu(side @ Wgc + bgc + (ego*side) @ Wbi + bbi)
// norms[row] = max(||ego_out[row]||_2, eps)
__global__ __launch_bounds__(256) void layer_gemm(
        const float* __restrict__ side, const float* __restrict__ ego,
        const float* __restrict__ Wgc,  const float* __restrict__ bgc,
        const float* __restrict__ Wbi,  const float* __restrict__ bbi,
        float* __restrict__ ego_out, float* __restrict__ norms) {
    __shared__ float S[64][D];
    __shared__ float P[64][D];
    const int r0  = blockIdx.x * 64;
    const int tid = threadIdx.x;

    // cooperative load: 64 rows x 128 cols of side & ego*side
    #pragma unroll
    for (int i = 0; i < 8; ++i) {
        int t  = tid + i * 256;       // among 64*32 float4 slots
        int rr = t >> 5;
        int q  = t & 31;
        int row = r0 + rr;
        float4 s4 = make_float4(0.f, 0.f, 0.f, 0.f);
        float4 e4 = make_float4(0.f, 0.f, 0.f, 0.f);
        if (row < NTOT) {
            s4 = *(const float4*)(side + (size_t)row * D + q * 4);
            e4 = *(const float4*)(ego  + (size_t)row * D + q * 4);
        }
        *(float4*)&S[rr][q * 4] = s4;
        float4 p4 = make_float4(s4.x * e4.x, s4.y * e4.y, s4.z * e4.z, s4.w * e4.w);
        *(float4*)&P[rr][q * 4] = p4;
    }
    __syncthreads();

    const int tc = tid & 31;   // col group: cols 4*tc .. 4*tc+3
    const int tr = tid >> 5;   // row group: rows tr*8 .. tr*8+7

    float acc[8][4];
    #pragma unroll
    for (int rr = 0; rr < 8; ++rr)
        #pragma unroll
        for (int c = 0; c < 4; ++c) acc[rr][c] = 0.f;

    for (int j = 0; j < D; ++j) {
        float4 wg = *(const float4*)(Wgc + (size_t)j * D + tc * 4);
        float4 wb = *(const float4*)(Wbi + (size_t)j * D + tc * 4);
        #pragma unroll
        for (int rr = 0; rr < 8; ++rr) {
            float s = S[tr * 8 + rr][j];
            float p = P[tr * 8 + rr][j];
            acc[rr][0] += s * wg.x + p * wb.x;
            acc[rr][1] += s * wg.y + p * wb.y;
            acc[rr][2] += s * wg.z + p * wb.z;
            acc[rr][3] += s * wg.w + p * wb.w;
        }
    }

    float4 bg = *(const float4*)(bgc + tc * 4);
    float4 bb = *(const float4*)(bbi + tc * 4);
    float bs0 = bg.x + bb.x, bs1 = bg.y + bb.y, bs2 = bg.z + bb.z, bs3 = bg.w + bb.w;

    #pragma unroll
    for (int rr = 0; rr < 8; ++rr) {
        int row = r0 + tr * 8 + rr;
        float o0 = acc[rr][0] + bs0;
        float o1 = acc[rr][1] + bs1;
        float o2 = acc[rr][2] + bs2;
        float o3 = acc[rr][3] + bs3;
        o0 = (o0 > 0.f) ? o0 : NEG_SLOPE * o0;
        o1 = (o1 > 0.f) ? o1 : NEG_SLOPE * o1;
        o2 = (o2 > 0.f) ? o2 : NEG_SLOPE * o2;
        o3 = (o3 > 0.f) ? o3 : NEG_SLOPE * o3;
        float sq = o0 * o0 + o1 * o1 + o2 * o2 + o3 * o3;
        // reduce across the 32 col-threads (lane = tc + 32*(tr&1); xor of bits<5 stays in half)
        #pragma unroll
        for (int off = 16; off >= 1; off >>= 1) sq += __shfl_xor(sq, off);
        if (row < NTOT) {
            *(float4*)(ego_out + (size_t)row * D + tc * 4) = make_float4(o0, o1, o2, o3);
            if (tc == 0) norms[row] = fmaxf(sqrtf(sq), EPS_);
        }
    }
}

// ---------------------------------------------------------------- final gather
__global__ void gather_out(const int* __restrict__ users,
                           const int* __restrict__ pos,
                           const int* __restrict__ neg,
                           const float* __restrict__ ego0,
                           const float* __restrict__ ego1,
                           const float* __restrict__ ego2,
                           const float* __restrict__ n1,
                           const float* __restrict__ n2,
                           float* __restrict__ out) {
    int t = blockIdx.x * blockDim.x + threadIdx.x;
    const int total = 3 * BATCH_ * 384;
    if (t >= total) return;
    int c = t % 384;
    int i = (t / 384) % BATCH_;
    int s = t / (384 * BATCH_);
    int node = (s == 0) ? users[i] : (s == 1 ? pos[i] + N_USER : neg[i] + N_USER);
    float val;
    if (c < 128)      val = ego0[(size_t)node * D + c];
    else if (c < 256) val = ego1[(size_t)node * D + (c - 128)] / n1[node];
    else              val = ego2[(size_t)node * D + (c - 256)] / n2[node];
    out[t] = val;
}

// ---------------------------------------------------------------- launch
extern "C" void kernel_launch(void* const* d_in, const int* in_sizes, int n_in,
                              void* d_out, int out_size, void* d_ws, size_t ws_size,
                              hipStream_t stream) {
    const int*   users     = (const int*)d_in[0];
    const int*   pos_items = (const int*)d_in[1];
    const int*   neg_items = (const int*)d_in[2];
    const float* user_emb  = (const float*)d_in[3];
    const float* item_emb1 = (const float*)d_in[4];
    const float* item_emb2 = (const float*)d_in[5];
    const float* feature   = (const float*)d_in[6];
    const float* w3        = (const float*)d_in[7];
    const float* W_gc      = (const float*)d_in[8];
    const float* b_gc      = (const float*)d_in[9];
    const float* W_bi      = (const float*)d_in[10];
    const float* b_bi      = (const float*)d_in[11];
    const int*   adj_rows  = (const int*)d_in[12];
    const int*   adj_cols  = (const int*)d_in[13];
    const float* adj_vals  = (const float*)d_in[14];
    const int nnz = in_sizes[14];

    float* ws   = (float*)d_ws;
    const size_t nd = (size_t)NTOT * D;
    float* ego0 = ws;
    float* ego1 = ego0 + nd;
    float* ego2 = ego1 + nd;
    float* side = ego2 + nd;
    float* n1   = side + nd;
    float* n2   = n1 + NTOT;

    float* out = (float*)d_out;

    // ego0
    {
        int total = NTOT * (D / 4);
        assemble_ego0<<<(total + 255) / 256, 256, 0, stream>>>(
            user_emb, item_emb1, item_emb2, feature, ego0);
    }

    for (int k = 0; k < 2; ++k) {
        const float* X = (k == 0) ? ego0 : ego1;
        float* egoN    = (k == 0) ? ego1 : ego2;
        float* nrm     = (k == 0) ? n1 : n2;

        hipMemsetAsync(side, 0, nd * sizeof(float), stream);
        spmm_atomic<<<4096, 256, 0, stream>>>(adj_rows, adj_cols, adj_vals, w3,
                                              X, side, nnz);
        layer_gemm<<<(NTOT + 63) / 64, 256, 0, stream>>>(
            side, X,
            W_gc + (size_t)k * D * D, b_gc + (size_t)k * D,
            W_bi + (size_t)k * D * D, b_bi + (size_t)k * D,
            egoN, nrm);
    }

    {
        int total = 3 * BATCH_ * 384;
        gather_out<<<(total + 255) / 256, 256, 0, stream>>>(
            users, pos_items, neg_items, ego0, ego1, ego2, n1, n2, out);
    }
}

// Round 2
// 1432.847 us; speedup vs baseline: 2.1662x; 2.1662x over previous
//
#include <hip/hip_runtime.h>
#include <math.h>

#define N_USER 50000
#define N_ITEM 50000
#define NTOT   100000
#define D      128
#define BATCH_ 4096
#define NEG_SLOPE 0.2f
#define EPS_ 1e-12f
#define SCAN_CHUNK 1024

// ---------------------------------------------------------------- ego0 assembly
__global__ void assemble_ego0(const float* __restrict__ user_emb,
                              const float* __restrict__ item_emb1,
                              const float* __restrict__ item_emb2,
                              const float* __restrict__ feature,
                              float* __restrict__ ego0) {
    int t = blockIdx.x * blockDim.x + threadIdx.x;   // float4 slot index
    const int total = NTOT * (D / 4);
    if (t >= total) return;
    int row = t >> 5;          // 32 float4 per row
    int q   = t & 31;
    int d0  = q * 4;
    const float* src;
    if (d0 < 64) {
        src = (row < N_USER) ? user_emb  + (size_t)row * 64 + d0
                             : item_emb1 + (size_t)(row - N_USER) * 64 + d0;
    } else {
        src = (row < N_USER) ? feature   + (size_t)row * 64 + (d0 - 64)
                             : item_emb2 + (size_t)(row - N_USER) * 64 + (d0 - 64);
    }
    float4 v = *(const float4*)src;
    *(float4*)(ego0 + (size_t)row * D + d0) = v;
}

// ---------------------------------------------------------------- CSR build
__global__ void hist_rows(const int* __restrict__ rows, int* __restrict__ cnt, int nnz) {
    int e = blockIdx.x * blockDim.x + threadIdx.x;
    if (e < nnz) atomicAdd(&cnt[rows[e]], 1);
}

// pass A: per-chunk sums (chunk = 1024 elements)
__global__ __launch_bounds__(1024) void scan_block_sums(const int* __restrict__ cnt,
                                                        int* __restrict__ bsum, int n) {
    __shared__ int ws[16];
    int i = blockIdx.x * SCAN_CHUNK + threadIdx.x;
    int x = (i < n) ? cnt[i] : 0;
    #pragma unroll
    for (int d = 32; d >= 1; d >>= 1) x += __shfl_xor(x, d);
    int wid = threadIdx.x >> 6, lane = threadIdx.x & 63;
    if (lane == 0) ws[wid] = x;
    __syncthreads();
    if (threadIdx.x == 0) {
        int s = 0;
        #pragma unroll
        for (int k = 0; k < 16; ++k) s += ws[k];
        bsum[blockIdx.x] = s;
    }
}

// pass B: tiny serial scan of chunk sums + total
__global__ void scan_small(const int* __restrict__ bsum, int* __restrict__ boff,
                           int nb, int* __restrict__ total_out) {
    if (threadIdx.x == 0 && blockIdx.x == 0) {
        int acc = 0;
        for (int i = 0; i < nb; ++i) { boff[i] = acc; acc += bsum[i]; }
        *total_out = acc;
    }
}

// pass C: exclusive scan within chunk + chunk offset
__global__ __launch_bounds__(1024) void scan_chunks(const int* __restrict__ cnt,
                                                    const int* __restrict__ boff,
                                                    int* __restrict__ off, int n) {
    __shared__ int ws[16];
    int tid = threadIdx.x;
    int i = blockIdx.x * SCAN_CHUNK + tid;
    int x = (i < n) ? cnt[i] : 0;
    int v = x;
    #pragma unroll
    for (int d = 1; d < 64; d <<= 1) { int u = __shfl_up(v, d); if ((tid & 63) >= d) v += u; }
    int wid = tid >> 6, lane = tid & 63;
    if (lane == 63) ws[wid] = v;
    __syncthreads();
    if (wid == 0) {
        int s = (lane < 16) ? ws[lane] : 0;
        #pragma unroll
        for (int d = 1; d < 16; d <<= 1) { int u = __shfl_up(s, d); if (lane >= d) s += u; }
        if (lane < 16) ws[lane] = s;
    }
    __syncthreads();
    int woff = (wid == 0) ? 0 : ws[wid - 1];
    if (i < n) off[i] = boff[blockIdx.x] + woff + v - x;
}

__global__ void csr_scatter(const int* __restrict__ rows, const int* __restrict__ cols,
                            const float* __restrict__ vals, const float* __restrict__ w3,
                            int* __restrict__ fill, int* __restrict__ ccol,
                            float* __restrict__ cval, int nnz) {
    int e = blockIdx.x * blockDim.x + threadIdx.x;
    if (e >= nnz) return;
    int r = rows[e];
    float v = vals[e];
    float v2 = v * v;
    float comb = w3[0] * v + w3[1] * v2 + w3[2] * v2 * v2 * v2;
    int pos = atomicAdd(&fill[r], 1);
    ccol[pos] = cols[e];
    cval[pos] = comb;
}

// ---------------------------------------------------------------- SpMM (CSR, wave/row)
__global__ __launch_bounds__(256) void spmm_csr(const int* __restrict__ row_off,
                                                const int* __restrict__ ccol,
                                                const float* __restrict__ cval,
                                                const float* __restrict__ X,
                                                float* __restrict__ side) {
    int row = (blockIdx.x * blockDim.x + threadIdx.x) >> 6;
    if (row >= NTOT) return;
    int lane = threadIdx.x & 63;
    int s = row_off[row], e = row_off[row + 1];
    float a0 = 0.f, a1 = 0.f;
    for (int i = s; i < e; ++i) {
        int   c = ccol[i];
        float v = cval[i];
        float2 x2 = *(const float2*)(X + (size_t)c * D + lane * 2);
        a0 += v * x2.x;
        a1 += v * x2.y;
    }
    *(float2*)(side + (size_t)row * D + lane * 2) = make_float2(a0, a1);
}

// ---------------------------------------------------------------- SpMM (atomic fallback)
__global__ void spmm_atomic(const int* __restrict__ rows, const int* __restrict__ cols,
                            const float* __restrict__ vals, const float* __restrict__ w3,
                            const float* __restrict__ X, float* __restrict__ side, int nnz) {
    const float w0 = w3[0], w1 = w3[1], w2 = w3[2];
    int lane   = threadIdx.x & 63;
    int gwave  = (blockIdx.x * blockDim.x + threadIdx.x) >> 6;
    int nwaves = (gridDim.x * blockDim.x) >> 6;
    for (int e = gwave; e < nnz; e += nwaves) {
        int   r = rows[e];
        int   c = cols[e];
        float v = vals[e];
        float v2   = v * v;
        float comb = w0 * v + w1 * v2 + w2 * v2 * v2 * v2;
        const float* xp = X    + (size_t)c * D;
        float*       sp = side + (size_t)r * D;
        atomicAdd(sp + lane,      comb * xp[lane]);
        atomicAdd(sp + lane + 64, comb * xp[lane + 64]);
    }
}

// ---------------------------------------------------------------- fused layer GEMM
__global__ __launch_bounds__(256) void layer_gemm(
        const float* __restrict__ side, const float* __restrict__ ego,
        const float* __restrict__ Wgc,  const float* __restrict__ bgc,
        const float* __restrict__ Wbi,  const float* __restrict__ bbi,
        float* __restrict__ ego_out, float* __restrict__ norms) {
    __shared__ float S[64][D];
    __shared__ float P[64][D];
    const int r0  = blockIdx.x * 64;
    const int tid = threadIdx.x;

    #pragma unroll
    for (int i = 0; i < 8; ++i) {
        int t  = tid + i * 256;
        int rr = t >> 5;
        int q  = t & 31;
        int row = r0 + rr;
        float4 s4 = make_float4(0.f, 0.f, 0.f, 0.f);
        float4 e4 = make_float4(0.f, 0.f, 0.f, 0.f);
        if (row < NTOT) {
            s4 = *(const float4*)(side + (size_t)row * D + q * 4);
            e4 = *(const float4*)(ego  + (size_t)row * D + q * 4);
        }
        *(float4*)&S[rr][q * 4] = s4;
        float4 p4 = make_float4(s4.x * e4.x, s4.y * e4.y, s4.z * e4.z, s4.w * e4.w);
        *(float4*)&P[rr][q * 4] = p4;
    }
    __syncthreads();

    const int tc = tid & 31;
    const int tr = tid >> 5;

    float acc[8][4];
    #pragma unroll
    for (int rr = 0; rr < 8; ++rr)
        #pragma unroll
        for (int c = 0; c < 4; ++c) acc[rr][c] = 0.f;

    for (int j = 0; j < D; ++j) {
        float4 wg = *(const float4*)(Wgc + (size_t)j * D + tc * 4);
        float4 wb = *(const float4*)(Wbi + (size_t)j * D + tc * 4);
        #pragma unroll
        for (int rr = 0; rr < 8; ++rr) {
            float s = S[tr * 8 + rr][j];
            float p = P[tr * 8 + rr][j];
            acc[rr][0] += s * wg.x + p * wb.x;
            acc[rr][1] += s * wg.y + p * wb.y;
            acc[rr][2] += s * wg.z + p * wb.z;
            acc[rr][3] += s * wg.w + p * wb.w;
        }
    }

    float4 bg = *(const float4*)(bgc + tc * 4);
    float4 bb = *(const float4*)(bbi + tc * 4);
    float bs0 = bg.x + bb.x, bs1 = bg.y + bb.y, bs2 = bg.z + bb.z, bs3 = bg.w + bb.w;

    #pragma unroll
    for (int rr = 0; rr < 8; ++rr) {
        int row = r0 + tr * 8 + rr;
        float o0 = acc[rr][0] + bs0;
        float o1 = acc[rr][1] + bs1;
        float o2 = acc[rr][2] + bs2;
        float o3 = acc[rr][3] + bs3;
        o0 = (o0 > 0.f) ? o0 : NEG_SLOPE * o0;
        o1 = (o1 > 0.f) ? o1 : NEG_SLOPE * o1;
        o2 = (o2 > 0.f) ? o2 : NEG_SLOPE * o2;
        o3 = (o3 > 0.f) ? o3 : NEG_SLOPE * o3;
        float sq = o0 * o0 + o1 * o1 + o2 * o2 + o3 * o3;
        #pragma unroll
        for (int off = 16; off >= 1; off >>= 1) sq += __shfl_xor(sq, off);
        if (row < NTOT) {
            *(float4*)(ego_out + (size_t)row * D + tc * 4) = make_float4(o0, o1, o2, o3);
            if (tc == 0) norms[row] = fmaxf(sqrtf(sq), EPS_);
        }
    }
}

// ---------------------------------------------------------------- final gather
__global__ void gather_out(const int* __restrict__ users,
                           const int* __restrict__ pos,
                           const int* __restrict__ neg,
                           const float* __restrict__ ego0,
                           const float* __restrict__ ego1,
                           const float* __restrict__ ego2,
                           const float* __restrict__ n1,
                           const float* __restrict__ n2,
                           float* __restrict__ out) {
    int t = blockIdx.x * blockDim.x + threadIdx.x;
    const int total = 3 * BATCH_ * 384;
    if (t >= total) return;
    int c = t % 384;
    int i = (t / 384) % BATCH_;
    int s = t / (384 * BATCH_);
    int node = (s == 0) ? users[i] : (s == 1 ? pos[i] + N_USER : neg[i] + N_USER);
    float val;
    if (c < 128)      val = ego0[(size_t)node * D + c];
    else if (c < 256) val = ego1[(size_t)node * D + (c - 128)] / n1[node];
    else              val = ego2[(size_t)node * D + (c - 256)] / n2[node];
    out[t] = val;
}

// ---------------------------------------------------------------- launch
extern "C" void kernel_launch(void* const* d_in, const int* in_sizes, int n_in,
                              void* d_out, int out_size, void* d_ws, size_t ws_size,
                              hipStream_t stream) {
    const int*   users     = (const int*)d_in[0];
    const int*   pos_items = (const int*)d_in[1];
    const int*   neg_items = (const int*)d_in[2];
    const float* user_emb  = (const float*)d_in[3];
    const float* item_emb1 = (const float*)d_in[4];
    const float* item_emb2 = (const float*)d_in[5];
    const float* feature   = (const float*)d_in[6];
    const float* w3        = (const float*)d_in[7];
    const float* W_gc      = (const float*)d_in[8];
    const float* b_gc      = (const float*)d_in[9];
    const float* W_bi      = (const float*)d_in[10];
    const float* b_bi      = (const float*)d_in[11];
    const int*   adj_rows  = (const int*)d_in[12];
    const int*   adj_cols  = (const int*)d_in[13];
    const float* adj_vals  = (const float*)d_in[14];
    const int nnz = in_sizes[14];

    const size_t nd = (size_t)NTOT * D;
    const int NB = (NTOT + SCAN_CHUNK - 1) / SCAN_CHUNK;

    float* ws   = (float*)d_ws;
    float* ego0 = ws;
    float* ego1 = ego0 + nd;
    float* ego2 = ego1 + nd;
    float* side = ego2 + nd;
    float* n1   = side + nd;
    float* n2   = n1 + NTOT;
    // integer region
    int*   row_off = (int*)(n2 + NTOT);          // NTOT+1
    int*   cnt     = row_off + (NTOT + 1);       // NTOT (histogram, then fill)
    int*   bsum    = cnt + NTOT;                 // NB
    int*   boff    = bsum + NB;                  // NB
    int*   ccol    = boff + NB;                  // nnz
    float* cval    = (float*)(ccol + nnz);       // nnz

    size_t required = ((char*)(cval + nnz)) - ((char*)d_ws);
    bool use_csr = (ws_size >= required);

    float* out = (float*)d_out;

    // ego0
    {
        int total = NTOT * (D / 4);
        assemble_ego0<<<(total + 255) / 256, 256, 0, stream>>>(
            user_emb, item_emb1, item_emb2, feature, ego0);
    }

    if (use_csr) {
        // ---- build CSR once (shared by both layers; comb folded into cval)
        hipMemsetAsync(cnt, 0, NTOT * sizeof(int), stream);
        hist_rows<<<(nnz + 255) / 256, 256, 0, stream>>>(adj_rows, cnt, nnz);
        scan_block_sums<<<NB, SCAN_CHUNK, 0, stream>>>(cnt, bsum, NTOT);
        scan_small<<<1, 64, 0, stream>>>(bsum, boff, NB, row_off + NTOT);
        scan_chunks<<<NB, SCAN_CHUNK, 0, stream>>>(cnt, boff, row_off, NTOT);
        hipMemcpyAsync(cnt, row_off, NTOT * sizeof(int), hipMemcpyDeviceToDevice, stream);
        csr_scatter<<<(nnz + 255) / 256, 256, 0, stream>>>(
            adj_rows, adj_cols, adj_vals, w3, cnt, ccol, cval, nnz);
    }

    for (int k = 0; k < 2; ++k) {
        const float* X = (k == 0) ? ego0 : ego1;
        float* egoN    = (k == 0) ? ego1 : ego2;
        float* nrm     = (k == 0) ? n1 : n2;

        if (use_csr) {
            spmm_csr<<<(NTOT * 64) / 256, 256, 0, stream>>>(row_off, ccol, cval, X, side);
        } else {
            hipMemsetAsync(side, 0, nd * sizeof(float), stream);
            spmm_atomic<<<4096, 256, 0, stream>>>(adj_rows, adj_cols, adj_vals, w3,
                                                  X, side, nnz);
        }
        layer_gemm<<<(NTOT + 63) / 64, 256, 0, stream>>>(
            side, X,
            W_gc + (size_t)k * D * D, b_gc + (size_t)k * D,
            W_bi + (size_t)k * D * D, b_bi + (size_t)k * D,
            egoN, nrm);
    }

    {
        int total = 3 * BATCH_ * 384;
        gather_out<<<(total + 255) / 256, 256, 0, stream>>>(
            users, pos_items, neg_items, ego0, ego1, ego2, n1, n2, out);
    }
}

// Round 3
// 731.952 us; speedup vs baseline: 4.2406x; 1.9576x over previous
//
#include <hip/hip_runtime.h>
#include <math.h>

#define N_USER 50000
#define N_ITEM 50000
#define NTOT   100000
#define D      128
#define BATCH_ 4096
#define NEG_SLOPE 0.2f
#define EPS_ 1e-12f
#define SCAN_CHUNK 1024

typedef __attribute__((ext_vector_type(8))) short bfrag;
typedef __attribute__((ext_vector_type(4))) float f32x4;

static __device__ __forceinline__ float bf2f(unsigned short h) {
    return __uint_as_float(((unsigned)h) << 16);
}
static __device__ __forceinline__ unsigned short f2bf(float f) {
    unsigned u = __float_as_uint(f);
    u += 0x7fffu + ((u >> 16) & 1u);   // round-to-nearest-even
    return (unsigned short)(u >> 16);
}

// ---------------------------------------------------------------- ego0 assembly (f32 + bf16)
__global__ void assemble_ego0(const float* __restrict__ user_emb,
                              const float* __restrict__ item_emb1,
                              const float* __restrict__ item_emb2,
                              const float* __restrict__ feature,
                              float* __restrict__ ego0f,
                              unsigned short* __restrict__ ego0h) {
    int t = blockIdx.x * blockDim.x + threadIdx.x;   // float4 slot
    const int total = NTOT * (D / 4);
    if (t >= total) return;
    int row = t >> 5;
    int q   = t & 31;
    int d0  = q * 4;
    const float* src;
    if (d0 < 64) {
        src = (row < N_USER) ? user_emb  + (size_t)row * 64 + d0
                             : item_emb1 + (size_t)(row - N_USER) * 64 + d0;
    } else {
        src = (row < N_USER) ? feature   + (size_t)row * 64 + (d0 - 64)
                             : item_emb2 + (size_t)(row - N_USER) * 64 + (d0 - 64);
    }
    float4 v = *(const float4*)src;
    *(float4*)(ego0f + (size_t)row * D + d0) = v;
    ushort4 h;
    h.x = f2bf(v.x); h.y = f2bf(v.y); h.z = f2bf(v.z); h.w = f2bf(v.w);
    *(ushort4*)(ego0h + (size_t)row * D + d0) = h;
}

// ---------------------------------------------------------------- W pre-pack (bf16, frag-major)
// layout index: ((((layer*2+mat)*4+kt)*8+nt)*64+lane)*8  (8 bf16 per lane)
__global__ void pack_w(const float* __restrict__ W_gc, const float* __restrict__ W_bi,
                       unsigned short* __restrict__ Wp) {
    int t = blockIdx.x * blockDim.x + threadIdx.x;
    if (t >= 8192) return;
    int lane  = t & 63;
    int nt    = (t >> 6) & 7;
    int kt    = (t >> 9) & 3;
    int mat   = (t >> 11) & 1;
    int layer = (t >> 12) & 1;
    const float* W = (mat ? W_bi : W_gc) + (size_t)layer * D * D;
    int n = nt * 16 + (lane & 15);
    int kbase = kt * 32 + (lane >> 4) * 8;
    unsigned short o8[8];
    #pragma unroll
    for (int e = 0; e < 8; ++e) o8[e] = f2bf(W[(size_t)(kbase + e) * D + n]);
    *(int4*)(Wp + (size_t)t * 8) = *(int4*)o8;
}

// ---------------------------------------------------------------- CSR build
__global__ void hist_rows(const int* __restrict__ rows, int* __restrict__ cnt, int nnz) {
    int e = blockIdx.x * blockDim.x + threadIdx.x;
    if (e < nnz) atomicAdd(&cnt[rows[e]], 1);
}

__global__ __launch_bounds__(1024) void scan_block_sums(const int* __restrict__ cnt,
                                                        int* __restrict__ bsum, int n) {
    __shared__ int ws[16];
    int i = blockIdx.x * SCAN_CHUNK + threadIdx.x;
    int x = (i < n) ? cnt[i] : 0;
    #pragma unroll
    for (int d = 32; d >= 1; d >>= 1) x += __shfl_xor(x, d);
    int wid = threadIdx.x >> 6, lane = threadIdx.x & 63;
    if (lane == 0) ws[wid] = x;
    __syncthreads();
    if (threadIdx.x == 0) {
        int s = 0;
        #pragma unroll
        for (int k = 0; k < 16; ++k) s += ws[k];
        bsum[blockIdx.x] = s;
    }
}

__global__ void scan_small(const int* __restrict__ bsum, int* __restrict__ boff,
                           int nb, int* __restrict__ total_out) {
    if (threadIdx.x == 0 && blockIdx.x == 0) {
        int acc = 0;
        for (int i = 0; i < nb; ++i) { boff[i] = acc; acc += bsum[i]; }
        *total_out = acc;
    }
}

__global__ __launch_bounds__(1024) void scan_chunks(const int* __restrict__ cnt,
                                                    const int* __restrict__ boff,
                                                    int* __restrict__ off, int n) {
    __shared__ int ws[16];
    int tid = threadIdx.x;
    int i = blockIdx.x * SCAN_CHUNK + tid;
    int x = (i < n) ? cnt[i] : 0;
    int v = x;
    #pragma unroll
    for (int d = 1; d < 64; d <<= 1) { int u = __shfl_up(v, d); if ((tid & 63) >= d) v += u; }
    int wid = tid >> 6, lane = tid & 63;
    if (lane == 63) ws[wid] = v;
    __syncthreads();
    if (wid == 0) {
        int s = (lane < 16) ? ws[lane] : 0;
        #pragma unroll
        for (int d = 1; d < 16; d <<= 1) { int u = __shfl_up(s, d); if (lane >= d) s += u; }
        if (lane < 16) ws[lane] = s;
    }
    __syncthreads();
    int woff = (wid == 0) ? 0 : ws[wid - 1];
    if (i < n) off[i] = boff[blockIdx.x] + woff + v - x;
}

__global__ void csr_scatter(const int* __restrict__ rows, const int* __restrict__ cols,
                            const float* __restrict__ vals, const float* __restrict__ w3,
                            int* __restrict__ fill, int2* __restrict__ edges, int nnz) {
    int e = blockIdx.x * blockDim.x + threadIdx.x;
    if (e >= nnz) return;
    int r = rows[e];
    float v = vals[e];
    float v2 = v * v;
    float comb = w3[0] * v + w3[1] * v2 + w3[2] * v2 * v2 * v2;
    int pos = atomicAdd(&fill[r], 1);
    edges[pos] = make_int2(cols[e], __float_as_int(comb));
}

// ---------------------------------------------------------------- SpMM (CSR, wave/row, bf16)
__global__ __launch_bounds__(256) void spmm_csr_h(const int* __restrict__ row_off,
                                                  const int2* __restrict__ edges,
                                                  const unsigned short* __restrict__ Xh,
                                                  unsigned short* __restrict__ side_h) {
    int row = (blockIdx.x * blockDim.x + threadIdx.x) >> 6;
    if (row >= NTOT) return;
    int lane = threadIdx.x & 63;
    int s = row_off[row], e = row_off[row + 1];
    float a0 = 0.f, a1 = 0.f;
    int i = s;
    for (; i + 1 < e; i += 2) {
        int2 e0 = edges[i];
        int2 e1 = edges[i + 1];
        float v0 = __int_as_float(e0.y);
        float v1 = __int_as_float(e1.y);
        ushort2 u0 = *(const ushort2*)(Xh + (size_t)e0.x * D + lane * 2);
        ushort2 u1 = *(const ushort2*)(Xh + (size_t)e1.x * D + lane * 2);
        a0 += v0 * bf2f(u0.x);
        a1 += v0 * bf2f(u0.y);
        a0 += v1 * bf2f(u1.x);
        a1 += v1 * bf2f(u1.y);
    }
    if (i < e) {
        int2 e0 = edges[i];
        float v0 = __int_as_float(e0.y);
        ushort2 u0 = *(const ushort2*)(Xh + (size_t)e0.x * D + lane * 2);
        a0 += v0 * bf2f(u0.x);
        a1 += v0 * bf2f(u0.y);
    }
    ushort2 o;
    o.x = f2bf(a0);
    o.y = f2bf(a1);
    *(ushort2*)(side_h + (size_t)row * D + lane * 2) = o;
}

// ---------------------------------------------------------------- fused MFMA layer GEMM
// ego_out_h = bf16(leaky(side@Wgc + bgc + (ego*side)@Wbi + bbi)); norms = row L2 norm (f32)
__global__ __launch_bounds__(256) void layer_gemm_mfma(
        const unsigned short* __restrict__ side_h,
        const unsigned short* __restrict__ ego_h,
        const unsigned short* __restrict__ Wp, int layer,
        const float* __restrict__ bgc, const float* __restrict__ bbi,
        unsigned short* __restrict__ ego_out_h, float* __restrict__ norms) {
    __shared__ unsigned short Sl[64 * D];
    __shared__ unsigned short Pl[64 * D];
    __shared__ float sqp[4][64];

    const int r0  = blockIdx.x * 64;
    const int tid = threadIdx.x;
    const int lane = tid & 63;
    const int wv   = tid >> 6;

    // ---- stage S (side) and P (ego*side) into LDS, bf16, XOR-swizzled
    #pragma unroll
    for (int it = 0; it < 4; ++it) {
        int c = tid + it * 256;          // 1024 chunks of 16B
        int r = c >> 4;
        int q = c & 15;
        int row = r0 + r;
        int4 sv = make_int4(0, 0, 0, 0), ev = make_int4(0, 0, 0, 0);
        if (row < NTOT) {
            sv = *(const int4*)(side_h + (size_t)row * D + q * 8);
            ev = *(const int4*)(ego_h  + (size_t)row * D + q * 8);
        }
        int dst = (r * 256 + q * 16) ^ ((r & 7) << 4);
        *(int4*)((char*)Sl + dst) = sv;
        const unsigned short* sp = (const unsigned short*)&sv;
        const unsigned short* ep = (const unsigned short*)&ev;
        unsigned short pv[8];
        #pragma unroll
        for (int j = 0; j < 8; ++j) pv[j] = f2bf(bf2f(sp[j]) * bf2f(ep[j]));
        *(int4*)((char*)Pl + dst) = *(int4*)pv;
    }

    // ---- W fragments (coalesced 16B/lane from packed layout)
    bfrag wg[4][2], wb[4][2];
    #pragma unroll
    for (int kt = 0; kt < 4; ++kt)
        #pragma unroll
        for (int n2 = 0; n2 < 2; ++n2) {
            int nt = wv * 2 + n2;
            size_t og = ((((size_t)(layer * 2 + 0) * 4 + kt) * 8 + nt) * 64 + lane) * 8;
            size_t ob = ((((size_t)(layer * 2 + 1) * 4 + kt) * 8 + nt) * 64 + lane) * 8;
            wg[kt][n2] = *(const bfrag*)(Wp + og);
            wb[kt][n2] = *(const bfrag*)(Wp + ob);
        }

    __syncthreads();

    // ---- MFMA main: acc[m][n] over 4 k-tiles, both matrices into same acc
    f32x4 acc[4][2];
    #pragma unroll
    for (int m = 0; m < 4; ++m)
        #pragma unroll
        for (int n = 0; n < 2; ++n) acc[m][n] = (f32x4){0.f, 0.f, 0.f, 0.f};

    #pragma unroll
    for (int kt = 0; kt < 4; ++kt) {
        bfrag sf[4], pf[4];
        #pragma unroll
        for (int m = 0; m < 4; ++m) {
            int rowl = m * 16 + (lane & 15);
            int byte = (rowl * 256 + kt * 64 + (lane >> 4) * 16) ^ ((rowl & 7) << 4);
            sf[m] = *(const bfrag*)((const char*)Sl + byte);
            pf[m] = *(const bfrag*)((const char*)Pl + byte);
        }
        #pragma unroll
        for (int m = 0; m < 4; ++m)
            #pragma unroll
            for (int n = 0; n < 2; ++n) {
                acc[m][n] = __builtin_amdgcn_mfma_f32_16x16x32_bf16(sf[m], wg[kt][n], acc[m][n], 0, 0, 0);
                acc[m][n] = __builtin_amdgcn_mfma_f32_16x16x32_bf16(pf[m], wb[kt][n], acc[m][n], 0, 0, 0);
            }
    }

    // ---- epilogue: bias + leaky + bf16 store + row-norm
    float bsum[2];
    #pragma unroll
    for (int n = 0; n < 2; ++n) {
        int col = wv * 32 + n * 16 + (lane & 15);
        bsum[n] = bgc[col] + bbi[col];
    }

    float sq[4][4];
    #pragma unroll
    for (int m = 0; m < 4; ++m)
        #pragma unroll
        for (int r = 0; r < 4; ++r) sq[m][r] = 0.f;

    #pragma unroll
    for (int m = 0; m < 4; ++m) {
        int rowl = m * 16 + (lane >> 4) * 4;
        #pragma unroll
        for (int n = 0; n < 2; ++n) {
            int col = wv * 32 + n * 16 + (lane & 15);
            #pragma unroll
            for (int r = 0; r < 4; ++r) {
                float o = acc[m][n][r] + bsum[n];
                o = (o > 0.f) ? o : NEG_SLOPE * o;
                sq[m][r] += o * o;
                int row = r0 + rowl + r;
                if (row < NTOT)
                    ego_out_h[(size_t)row * D + col] = f2bf(o);
            }
        }
    }

    // reduce sq over the 16 lanes sharing a row (bits 0-3 of lane)
    #pragma unroll
    for (int m = 0; m < 4; ++m)
        #pragma unroll
        for (int r = 0; r < 4; ++r) {
            float v = sq[m][r];
            #pragma unroll
            for (int off = 8; off >= 1; off >>= 1) v += __shfl_xor(v, off);
            if ((lane & 15) == 0) sqp[wv][m * 16 + (lane >> 4) * 4 + r] = v;
        }
    __syncthreads();
    if (tid < 64) {
        int row = r0 + tid;
        if (row < NTOT) {
            float s = sqp[0][tid] + sqp[1][tid] + sqp[2][tid] + sqp[3][tid];
            norms[row] = fmaxf(sqrtf(s), EPS_);
        }
    }
}

// ---------------------------------------------------------------- final gather
__global__ void gather_out(const int* __restrict__ users,
                           const int* __restrict__ pos,
                           const int* __restrict__ neg,
                           const float* __restrict__ ego0f,
                           const unsigned short* __restrict__ ego1h,
                           const unsigned short* __restrict__ ego2h,
                           const float* __restrict__ n1,
                           const float* __restrict__ n2,
                           float* __restrict__ out) {
    int t = blockIdx.x * blockDim.x + threadIdx.x;
    const int total = 3 * BATCH_ * 384;
    if (t >= total) return;
    int c = t % 384;
    int i = (t / 384) % BATCH_;
    int s = t / (384 * BATCH_);
    int node = (s == 0) ? users[i] : (s == 1 ? pos[i] + N_USER : neg[i] + N_USER);
    float val;
    if (c < 128)      val = ego0f[(size_t)node * D + c];
    else if (c < 256) val = bf2f(ego1h[(size_t)node * D + (c - 128)]) / n1[node];
    else              val = bf2f(ego2h[(size_t)node * D + (c - 256)]) / n2[node];
    out[t] = val;
}

// ---------------------------------------------------------------- launch
extern "C" void kernel_launch(void* const* d_in, const int* in_sizes, int n_in,
                              void* d_out, int out_size, void* d_ws, size_t ws_size,
                              hipStream_t stream) {
    const int*   users     = (const int*)d_in[0];
    const int*   pos_items = (const int*)d_in[1];
    const int*   neg_items = (const int*)d_in[2];
    const float* user_emb  = (const float*)d_in[3];
    const float* item_emb1 = (const float*)d_in[4];
    const float* item_emb2 = (const float*)d_in[5];
    const float* feature   = (const float*)d_in[6];
    const float* w3        = (const float*)d_in[7];
    const float* W_gc      = (const float*)d_in[8];
    const float* b_gc      = (const float*)d_in[9];
    const float* W_bi      = (const float*)d_in[10];
    const float* b_bi      = (const float*)d_in[11];
    const int*   adj_rows  = (const int*)d_in[12];
    const int*   adj_cols  = (const int*)d_in[13];
    const float* adj_vals  = (const float*)d_in[14];
    const int nnz = in_sizes[14];

    const size_t nd = (size_t)NTOT * D;
    const int NB = (NTOT + SCAN_CHUNK - 1) / SCAN_CHUNK;   // 98

    char* p = (char*)d_ws;
    float* ego0f = (float*)p;                 p += nd * 4;
    float* n1    = (float*)p;                 p += NTOT * 4;
    float* n2    = (float*)p;                 p += NTOT * 4;
    unsigned short* ego0h  = (unsigned short*)p; p += nd * 2;
    unsigned short* ego1h  = (unsigned short*)p; p += nd * 2;
    unsigned short* ego2h  = (unsigned short*)p; p += nd * 2;
    unsigned short* side_h = (unsigned short*)p; p += nd * 2;
    unsigned short* Wp     = (unsigned short*)p; p += 8192 * 8 * 2;
    int*  row_off = (int*)p;                  p += (NTOT + 4) * 4;
    int*  cnt     = (int*)p;                  p += NTOT * 4;
    int*  bsum    = (int*)p;                  p += 128 * 4;
    int*  boff    = (int*)p;                  p += 128 * 4;
    int2* edges   = (int2*)p;                 p += (size_t)nnz * 8;

    float* out = (float*)d_out;

    // ego0 (f32 + bf16)
    {
        int total = NTOT * (D / 4);
        assemble_ego0<<<(total + 255) / 256, 256, 0, stream>>>(
            user_emb, item_emb1, item_emb2, feature, ego0f, ego0h);
    }
    // W pack
    pack_w<<<8192 / 256, 256, 0, stream>>>(W_gc, W_bi, Wp);

    // CSR build (shared by both layers; comb folded into edge payload)
    hipMemsetAsync(cnt, 0, NTOT * sizeof(int), stream);
    hist_rows<<<(nnz + 255) / 256, 256, 0, stream>>>(adj_rows, cnt, nnz);
    scan_block_sums<<<NB, SCAN_CHUNK, 0, stream>>>(cnt, bsum, NTOT);
    scan_small<<<1, 64, 0, stream>>>(bsum, boff, NB, row_off + NTOT);
    scan_chunks<<<NB, SCAN_CHUNK, 0, stream>>>(cnt, boff, row_off, NTOT);
    hipMemcpyAsync(cnt, row_off, NTOT * sizeof(int), hipMemcpyDeviceToDevice, stream);
    csr_scatter<<<(nnz + 255) / 256, 256, 0, stream>>>(
        adj_rows, adj_cols, adj_vals, w3, cnt, edges, nnz);

    for (int k = 0; k < 2; ++k) {
        const unsigned short* Xh = (k == 0) ? ego0h : ego1h;
        unsigned short* egoNh    = (k == 0) ? ego1h : ego2h;
        float* nrm               = (k == 0) ? n1 : n2;

        spmm_csr_h<<<(NTOT * 64) / 256, 256, 0, stream>>>(row_off, edges, Xh, side_h);
        layer_gemm_mfma<<<(NTOT + 63) / 64, 256, 0, stream>>>(
            side_h, Xh, Wp, k,
            b_gc + (size_t)k * D, b_bi + (size_t)k * D,
            egoNh, nrm);
    }

    {
        int total = 3 * BATCH_ * 384;
        gather_out<<<(total + 255) / 256, 256, 0, stream>>>(
            users, pos_items, neg_items, ego0f, ego1h, ego2h, n1, n2, out);
    }
}

// Round 4
// 585.187 us; speedup vs baseline: 5.3041x; 1.2508x over previous
//
#include <hip/hip_runtime.h>
#include <math.h>

#define N_USER 50000
#define N_ITEM 50000
#define NTOT   100000
#define D      128
#define BATCH_ 4096
#define NEG_SLOPE 0.2f
#define EPS_ 1e-12f
#define SCAN_CHUNK 1024
#define SCAT_CHUNKS 256          // edge chunks for sliced scatter
#define ROWS_PER_SLICE (NTOT / 8)

typedef __attribute__((ext_vector_type(8))) short bfrag;
typedef __attribute__((ext_vector_type(4))) float f32x4;

static __device__ __forceinline__ float bf2f(unsigned short h) {
    return __uint_as_float(((unsigned)h) << 16);
}
static __device__ __forceinline__ unsigned short f2bf(float f) {
    unsigned u = __float_as_uint(f);
    u += 0x7fffu + ((u >> 16) & 1u);   // round-to-nearest-even
    return (unsigned short)(u >> 16);
}

// ---------------------------------------------------------------- ego0 assembly (bf16 only)
__global__ void assemble_ego0(const float* __restrict__ user_emb,
                              const float* __restrict__ item_emb1,
                              const float* __restrict__ item_emb2,
                              const float* __restrict__ feature,
                              unsigned short* __restrict__ ego0h) {
    int t = blockIdx.x * blockDim.x + threadIdx.x;   // float4 slot
    const int total = NTOT * (D / 4);
    if (t >= total) return;
    int row = t >> 5;
    int q   = t & 31;
    int d0  = q * 4;
    const float* src;
    if (d0 < 64) {
        src = (row < N_USER) ? user_emb  + (size_t)row * 64 + d0
                             : item_emb1 + (size_t)(row - N_USER) * 64 + d0;
    } else {
        src = (row < N_USER) ? feature   + (size_t)row * 64 + (d0 - 64)
                             : item_emb2 + (size_t)(row - N_USER) * 64 + (d0 - 64);
    }
    float4 v = *(const float4*)src;
    ushort4 h;
    h.x = f2bf(v.x); h.y = f2bf(v.y); h.z = f2bf(v.z); h.w = f2bf(v.w);
    *(ushort4*)(ego0h + (size_t)row * D + d0) = h;
}

// ---------------------------------------------------------------- W pre-pack (bf16, frag-major)
__global__ void pack_w(const float* __restrict__ W_gc, const float* __restrict__ W_bi,
                       unsigned short* __restrict__ Wp) {
    int t = blockIdx.x * blockDim.x + threadIdx.x;
    if (t >= 8192) return;
    int lane  = t & 63;
    int nt    = (t >> 6) & 7;
    int kt    = (t >> 9) & 3;
    int mat   = (t >> 11) & 1;
    int layer = (t >> 12) & 1;
    const float* W = (mat ? W_bi : W_gc) + (size_t)layer * D * D;
    int n = nt * 16 + (lane & 15);
    int kbase = kt * 32 + (lane >> 4) * 8;
    unsigned short o8[8];
    #pragma unroll
    for (int e = 0; e < 8; ++e) o8[e] = f2bf(W[(size_t)(kbase + e) * D + n]);
    *(int4*)(Wp + (size_t)t * 8) = *(int4*)o8;
}

// ---------------------------------------------------------------- CSR build
__global__ void hist_rows(const int* __restrict__ rows, int* __restrict__ cnt, int nnz) {
    int e = blockIdx.x * blockDim.x + threadIdx.x;
    if (e < nnz) atomicAdd(&cnt[rows[e]], 1);
}

__global__ __launch_bounds__(1024) void scan_block_sums(const int* __restrict__ cnt,
                                                        int* __restrict__ bsum, int n) {
    __shared__ int ws[16];
    int i = blockIdx.x * SCAN_CHUNK + threadIdx.x;
    int x = (i < n) ? cnt[i] : 0;
    #pragma unroll
    for (int d = 32; d >= 1; d >>= 1) x += __shfl_xor(x, d);
    int wid = threadIdx.x >> 6, lane = threadIdx.x & 63;
    if (lane == 0) ws[wid] = x;
    __syncthreads();
    if (threadIdx.x == 0) {
        int s = 0;
        #pragma unroll
        for (int k = 0; k < 16; ++k) s += ws[k];
        bsum[blockIdx.x] = s;
    }
}

__global__ void scan_small(const int* __restrict__ bsum, int* __restrict__ boff,
                           int nb, int* __restrict__ total_out) {
    if (threadIdx.x == 0 && blockIdx.x == 0) {
        int acc = 0;
        for (int i = 0; i < nb; ++i) { boff[i] = acc; acc += bsum[i]; }
        *total_out = acc;
    }
}

// writes exclusive scan to BOTH row_off and fill (working cursor copy)
__global__ __launch_bounds__(1024) void scan_chunks(const int* __restrict__ cnt,
                                                    const int* __restrict__ boff,
                                                    int* __restrict__ off,
                                                    int* __restrict__ fill, int n) {
    __shared__ int ws[16];
    int tid = threadIdx.x;
    int i = blockIdx.x * SCAN_CHUNK + tid;
    int x = (i < n) ? cnt[i] : 0;
    int v = x;
    #pragma unroll
    for (int d = 1; d < 64; d <<= 1) { int u = __shfl_up(v, d); if ((tid & 63) >= d) v += u; }
    int wid = tid >> 6, lane = tid & 63;
    if (lane == 63) ws[wid] = v;
    __syncthreads();
    if (wid == 0) {
        int s = (lane < 16) ? ws[lane] : 0;
        #pragma unroll
        for (int d = 1; d < 16; d <<= 1) { int u = __shfl_up(s, d); if (lane >= d) s += u; }
        if (lane < 16) ws[lane] = s;
    }
    __syncthreads();
    int woff = (wid == 0) ? 0 : ws[wid - 1];
    if (i < n) {
        int o = boff[blockIdx.x] + woff + v - x;
        off[i]  = o;
        fill[i] = o;
    }
}

// sliced scatter: block b -> slice (b&7) owns rows [s*12500, (s+1)*12500),
// chunk (b>>3) of the edge list. With round-robin block->XCD dispatch each
// slice's 3.2MB dest region stays in one XCD's L2 (perf heuristic only;
// correct under any mapping).
__global__ __launch_bounds__(256) void csr_scatter_sliced(
        const int* __restrict__ rows, const int* __restrict__ cols,
        const float* __restrict__ vals, const float* __restrict__ w3,
        int* __restrict__ fill, int2* __restrict__ edges, int nnz, int chunk_sz) {
    int slice = blockIdx.x & 7;
    int chunk = blockIdx.x >> 3;
    int lo = slice * ROWS_PER_SLICE;
    int hi = lo + ROWS_PER_SLICE;
    const float w0 = w3[0], w1 = w3[1], w2 = w3[2];
    int base = chunk * chunk_sz;
    int end  = min(base + chunk_sz, nnz);
    for (int e = base + threadIdx.x; e < end; e += 256) {
        int r = rows[e];
        if (r >= lo && r < hi) {
            float v = vals[e];
            int   c = cols[e];
            float v2 = v * v;
            float comb = w0 * v + w1 * v2 + w2 * v2 * v2 * v2;
            int pos = atomicAdd(&fill[r], 1);
            edges[pos] = make_int2(c, __float_as_int(comb));
        }
    }
}

// ---------------------------------------------------------------- SpMM (CSR, wave/row, 4-edge groups)
__global__ __launch_bounds__(256) void spmm_csr_h(const int* __restrict__ row_off,
                                                  const int2* __restrict__ edges,
                                                  const unsigned short* __restrict__ Xh,
                                                  unsigned short* __restrict__ side_h) {
    int row = (blockIdx.x * blockDim.x + threadIdx.x) >> 6;
    if (row >= NTOT) return;
    int lane = threadIdx.x & 63;
    int g = lane >> 4;        // edge slot 0..3
    int q = lane & 15;        // dim slice: dims q*8 .. q*8+7
    int s = row_off[row], e = row_off[row + 1];

    float a[8];
    #pragma unroll
    for (int j = 0; j < 8; ++j) a[j] = 0.f;

    for (int i = s; i < e; i += 8) {
        int i0 = i + g, i1 = i + 4 + g;
        int2 e0 = (i0 < e) ? edges[i0] : make_int2(0, 0);
        int2 e1 = (i1 < e) ? edges[i1] : make_int2(0, 0);
        float v0 = __int_as_float(e0.y);
        float v1 = __int_as_float(e1.y);
        int4 x0 = *(const int4*)(Xh + (size_t)e0.x * D + q * 8);
        int4 x1 = *(const int4*)(Xh + (size_t)e1.x * D + q * 8);
        const unsigned short* p0 = (const unsigned short*)&x0;
        const unsigned short* p1 = (const unsigned short*)&x1;
        #pragma unroll
        for (int j = 0; j < 8; ++j)
            a[j] += v0 * bf2f(p0[j]) + v1 * bf2f(p1[j]);
    }
    // reduce the 4 edge-slot groups (lane^16, lane^32)
    #pragma unroll
    for (int j = 0; j < 8; ++j) {
        a[j] += __shfl_xor(a[j], 16);
        a[j] += __shfl_xor(a[j], 32);
    }
    if (g == 0) {
        unsigned short o[8];
        #pragma unroll
        for (int j = 0; j < 8; ++j) o[j] = f2bf(a[j]);
        *(int4*)(side_h + (size_t)row * D + q * 8) = *(int4*)o;
    }
}

// ---------------------------------------------------------------- fused MFMA layer GEMM
__global__ __launch_bounds__(256) void layer_gemm_mfma(
        const unsigned short* __restrict__ side_h,
        const unsigned short* __restrict__ ego_h,
        const unsigned short* __restrict__ Wp, int layer,
        const float* __restrict__ bgc, const float* __restrict__ bbi,
        unsigned short* __restrict__ ego_out_h, float* __restrict__ norms) {
    __shared__ unsigned short Sl[64 * D];
    __shared__ unsigned short Pl[64 * D];
    __shared__ float sqp[4][64];

    const int r0  = blockIdx.x * 64;
    const int tid = threadIdx.x;
    const int lane = tid & 63;
    const int wv   = tid >> 6;

    #pragma unroll
    for (int it = 0; it < 4; ++it) {
        int c = tid + it * 256;          // 1024 chunks of 16B
        int r = c >> 4;
        int q = c & 15;
        int row = r0 + r;
        int4 sv = make_int4(0, 0, 0, 0), ev = make_int4(0, 0, 0, 0);
        if (row < NTOT) {
            sv = *(const int4*)(side_h + (size_t)row * D + q * 8);
            ev = *(const int4*)(ego_h  + (size_t)row * D + q * 8);
        }
        int dst = (r * 256 + q * 16) ^ ((r & 7) << 4);
        *(int4*)((char*)Sl + dst) = sv;
        const unsigned short* sp = (const unsigned short*)&sv;
        const unsigned short* ep = (const unsigned short*)&ev;
        unsigned short pv[8];
        #pragma unroll
        for (int j = 0; j < 8; ++j) pv[j] = f2bf(bf2f(sp[j]) * bf2f(ep[j]));
        *(int4*)((char*)Pl + dst) = *(int4*)pv;
    }

    bfrag wg[4][2], wb[4][2];
    #pragma unroll
    for (int kt = 0; kt < 4; ++kt)
        #pragma unroll
        for (int n2 = 0; n2 < 2; ++n2) {
            int nt = wv * 2 + n2;
            size_t og = ((((size_t)(layer * 2 + 0) * 4 + kt) * 8 + nt) * 64 + lane) * 8;
            size_t ob = ((((size_t)(layer * 2 + 1) * 4 + kt) * 8 + nt) * 64 + lane) * 8;
            wg[kt][n2] = *(const bfrag*)(Wp + og);
            wb[kt][n2] = *(const bfrag*)(Wp + ob);
        }

    __syncthreads();

    f32x4 acc[4][2];
    #pragma unroll
    for (int m = 0; m < 4; ++m)
        #pragma unroll
        for (int n = 0; n < 2; ++n) acc[m][n] = (f32x4){0.f, 0.f, 0.f, 0.f};

    #pragma unroll
    for (int kt = 0; kt < 4; ++kt) {
        bfrag sf[4], pf[4];
        #pragma unroll
        for (int m = 0; m < 4; ++m) {
            int rowl = m * 16 + (lane & 15);
            int byte = (rowl * 256 + kt * 64 + (lane >> 4) * 16) ^ ((rowl & 7) << 4);
            sf[m] = *(const bfrag*)((const char*)Sl + byte);
            pf[m] = *(const bfrag*)((const char*)Pl + byte);
        }
        #pragma unroll
        for (int m = 0; m < 4; ++m)
            #pragma unroll
            for (int n = 0; n < 2; ++n) {
                acc[m][n] = __builtin_amdgcn_mfma_f32_16x16x32_bf16(sf[m], wg[kt][n], acc[m][n], 0, 0, 0);
                acc[m][n] = __builtin_amdgcn_mfma_f32_16x16x32_bf16(pf[m], wb[kt][n], acc[m][n], 0, 0, 0);
            }
    }

    float bsum[2];
    #pragma unroll
    for (int n = 0; n < 2; ++n) {
        int col = wv * 32 + n * 16 + (lane & 15);
        bsum[n] = bgc[col] + bbi[col];
    }

    float sq[4][4];
    #pragma unroll
    for (int m = 0; m < 4; ++m)
        #pragma unroll
        for (int r = 0; r < 4; ++r) sq[m][r] = 0.f;

    #pragma unroll
    for (int m = 0; m < 4; ++m) {
        int rowl = m * 16 + (lane >> 4) * 4;
        #pragma unroll
        for (int n = 0; n < 2; ++n) {
            int col = wv * 32 + n * 16 + (lane & 15);
            #pragma unroll
            for (int r = 0; r < 4; ++r) {
                float o = acc[m][n][r] + bsum[n];
                o = (o > 0.f) ? o : NEG_SLOPE * o;
                sq[m][r] += o * o;
                int row = r0 + rowl + r;
                if (row < NTOT)
                    ego_out_h[(size_t)row * D + col] = f2bf(o);
            }
        }
    }

    #pragma unroll
    for (int m = 0; m < 4; ++m)
        #pragma unroll
        for (int r = 0; r < 4; ++r) {
            float v = sq[m][r];
            #pragma unroll
            for (int off = 8; off >= 1; off >>= 1) v += __shfl_xor(v, off);
            if ((lane & 15) == 0) sqp[wv][m * 16 + (lane >> 4) * 4 + r] = v;
        }
    __syncthreads();
    if (tid < 64) {
        int row = r0 + tid;
        if (row < NTOT) {
            float s = sqp[0][tid] + sqp[1][tid] + sqp[2][tid] + sqp[3][tid];
            norms[row] = fmaxf(sqrtf(s), EPS_);
        }
    }
}

// ---------------------------------------------------------------- final gather (layer0 from raw f32 inputs)
__global__ void gather_out(const int* __restrict__ users,
                           const int* __restrict__ pos,
                           const int* __restrict__ neg,
                           const float* __restrict__ user_emb,
                           const float* __restrict__ item_emb1,
                           const float* __restrict__ item_emb2,
                           const float* __restrict__ feature,
                           const unsigned short* __restrict__ ego1h,
                           const unsigned short* __restrict__ ego2h,
                           const float* __restrict__ n1,
                           const float* __restrict__ n2,
                           float* __restrict__ out) {
    int t = blockIdx.x * blockDim.x + threadIdx.x;
    const int total = 3 * BATCH_ * 384;
    if (t >= total) return;
    int c = t % 384;
    int i = (t / 384) % BATCH_;
    int s = t / (384 * BATCH_);
    int idx  = (s == 0) ? users[i] : (s == 1 ? pos[i] : neg[i]);     // local index
    int node = (s == 0) ? idx : idx + N_USER;                         // global node
    float val;
    if (c < 128) {
        if (s == 0)
            val = (c < 64) ? user_emb[(size_t)idx * 64 + c]
                           : feature[(size_t)idx * 64 + (c - 64)];
        else
            val = (c < 64) ? item_emb1[(size_t)idx * 64 + c]
                           : item_emb2[(size_t)idx * 64 + (c - 64)];
    } else if (c < 256) {
        val = bf2f(ego1h[(size_t)node * D + (c - 128)]) / n1[node];
    } else {
        val = bf2f(ego2h[(size_t)node * D + (c - 256)]) / n2[node];
    }
    out[t] = val;
}

// ---------------------------------------------------------------- launch
extern "C" void kernel_launch(void* const* d_in, const int* in_sizes, int n_in,
                              void* d_out, int out_size, void* d_ws, size_t ws_size,
                              hipStream_t stream) {
    const int*   users     = (const int*)d_in[0];
    const int*   pos_items = (const int*)d_in[1];
    const int*   neg_items = (const int*)d_in[2];
    const float* user_emb  = (const float*)d_in[3];
    const float* item_emb1 = (const float*)d_in[4];
    const float* item_emb2 = (const float*)d_in[5];
    const float* feature   = (const float*)d_in[6];
    const float* w3        = (const float*)d_in[7];
    const float* W_gc      = (const float*)d_in[8];
    const float* b_gc      = (const float*)d_in[9];
    const float* W_bi      = (const float*)d_in[10];
    const float* b_bi      = (const float*)d_in[11];
    const int*   adj_rows  = (const int*)d_in[12];
    const int*   adj_cols  = (const int*)d_in[13];
    const float* adj_vals  = (const float*)d_in[14];
    const int nnz = in_sizes[14];

    const size_t nd = (size_t)NTOT * D;
    const int NB = (NTOT + SCAN_CHUNK - 1) / SCAN_CHUNK;   // 98

    char* p = (char*)d_ws;
    float* n1    = (float*)p;                 p += NTOT * 4;
    float* n2    = (float*)p;                 p += NTOT * 4;
    unsigned short* ego0h  = (unsigned short*)p; p += nd * 2;
    unsigned short* ego1h  = (unsigned short*)p; p += nd * 2;
    unsigned short* ego2h  = (unsigned short*)p; p += nd * 2;
    unsigned short* side_h = (unsigned short*)p; p += nd * 2;
    unsigned short* Wp     = (unsigned short*)p; p += 8192 * 8 * 2;
    int*  row_off = (int*)p;                  p += (NTOT + 4) * 4;
    int*  cnt     = (int*)p;                  p += NTOT * 4;
    int*  bsum    = (int*)p;                  p += 128 * 4;
    int*  boff    = (int*)p;                  p += 128 * 4;
    int2* edges   = (int2*)p;                 p += (size_t)nnz * 8;

    float* out = (float*)d_out;

    // ego0 bf16
    {
        int total = NTOT * (D / 4);
        assemble_ego0<<<(total + 255) / 256, 256, 0, stream>>>(
            user_emb, item_emb1, item_emb2, feature, ego0h);
    }
    pack_w<<<8192 / 256, 256, 0, stream>>>(W_gc, W_bi, Wp);

    // CSR build
    hipMemsetAsync(cnt, 0, NTOT * sizeof(int), stream);
    hist_rows<<<(nnz + 255) / 256, 256, 0, stream>>>(adj_rows, cnt, nnz);
    scan_block_sums<<<NB, SCAN_CHUNK, 0, stream>>>(cnt, bsum, NTOT);
    scan_small<<<1, 64, 0, stream>>>(bsum, boff, NB, row_off + NTOT);
    scan_chunks<<<NB, SCAN_CHUNK, 0, stream>>>(cnt, boff, row_off, cnt, NTOT);
    {
        int chunk_sz = (nnz + SCAT_CHUNKS - 1) / SCAT_CHUNKS;
        csr_scatter_sliced<<<SCAT_CHUNKS * 8, 256, 0, stream>>>(
            adj_rows, adj_cols, adj_vals, w3, cnt, edges, nnz, chunk_sz);
    }

    for (int k = 0; k < 2; ++k) {
        const unsigned short* Xh = (k == 0) ? ego0h : ego1h;
        unsigned short* egoNh    = (k == 0) ? ego1h : ego2h;
        float* nrm               = (k == 0) ? n1 : n2;

        spmm_csr_h<<<(NTOT + 3) / 4, 256, 0, stream>>>(row_off, edges, Xh, side_h);
        layer_gemm_mfma<<<(NTOT + 63) / 64, 256, 0, stream>>>(
            side_h, Xh, Wp, k,
            b_gc + (size_t)k * D, b_bi + (size_t)k * D,
            egoNh, nrm);
    }

    {
        int total = 3 * BATCH_ * 384;
        gather_out<<<(total + 255) / 256, 256, 0, stream>>>(
            users, pos_items, neg_items,
            user_emb, item_emb1, item_emb2, feature,
            ego1h, ego2h, n1, n2, out);
    }
}

// Round 5
// 444.075 us; speedup vs baseline: 6.9896x; 1.3178x over previous
//
#include <hip/hip_runtime.h>
#include <math.h>

#define N_USER 50000
#define N_ITEM 50000
#define NTOT   100000
#define D      128
#define BATCH_ 4096
#define NEG_SLOPE 0.2f
#define EPS_ 1e-12f
#define SCAN_CHUNK 1024
#define NBUK 782            // buckets of 128 rows
#define NCHK 128            // edge chunks for partition
#define NSCAN (NBUK * NCHK) // 100096
#define BUKCAP 12288        // max edges/bucket for LDS sort (mean 4092)

typedef __attribute__((ext_vector_type(8))) short bfrag;
typedef __attribute__((ext_vector_type(4))) float f32x4;

static __device__ __forceinline__ float bf2f(unsigned short h) {
    return __uint_as_float(((unsigned)h) << 16);
}
static __device__ __forceinline__ unsigned short f2bf(float f) {
    unsigned u = __float_as_uint(f);
    u += 0x7fffu + ((u >> 16) & 1u);   // round-to-nearest-even
    return (unsigned short)(u >> 16);
}

// ---------------------------------------------------------------- ego0 assembly (bf16 only)
__global__ void assemble_ego0(const float* __restrict__ user_emb,
                              const float* __restrict__ item_emb1,
                              const float* __restrict__ item_emb2,
                              const float* __restrict__ feature,
                              unsigned short* __restrict__ ego0h) {
    int t = blockIdx.x * blockDim.x + threadIdx.x;   // float4 slot
    const int total = NTOT * (D / 4);
    if (t >= total) return;
    int row = t >> 5;
    int q   = t & 31;
    int d0  = q * 4;
    const float* src;
    if (d0 < 64) {
        src = (row < N_USER) ? user_emb  + (size_t)row * 64 + d0
                             : item_emb1 + (size_t)(row - N_USER) * 64 + d0;
    } else {
        src = (row < N_USER) ? feature   + (size_t)row * 64 + (d0 - 64)
                             : item_emb2 + (size_t)(row - N_USER) * 64 + (d0 - 64);
    }
    float4 v = *(const float4*)src;
    ushort4 h;
    h.x = f2bf(v.x); h.y = f2bf(v.y); h.z = f2bf(v.z); h.w = f2bf(v.w);
    *(ushort4*)(ego0h + (size_t)row * D + d0) = h;
}

// ---------------------------------------------------------------- W pre-pack (bf16, frag-major)
__global__ void pack_w(const float* __restrict__ W_gc, const float* __restrict__ W_bi,
                       unsigned short* __restrict__ Wp) {
    int t = blockIdx.x * blockDim.x + threadIdx.x;
    if (t >= 8192) return;
    int lane  = t & 63;
    int nt    = (t >> 6) & 7;
    int kt    = (t >> 9) & 3;
    int mat   = (t >> 11) & 1;
    int layer = (t >> 12) & 1;
    const float* W = (mat ? W_bi : W_gc) + (size_t)layer * D * D;
    int n = nt * 16 + (lane & 15);
    int kbase = kt * 32 + (lane >> 4) * 8;
    unsigned short o8[8];
    #pragma unroll
    for (int e = 0; e < 8; ++e) o8[e] = f2bf(W[(size_t)(kbase + e) * D + n]);
    *(int4*)(Wp + (size_t)t * 8) = *(int4*)o8;
}

// ---------------------------------------------------------------- bucket histogram (chunk-blocks)
__global__ __launch_bounds__(256) void hist_buckets(const int* __restrict__ rows,
                                                    int* __restrict__ cnt2,
                                                    int nnz, int chunk_sz) {
    __shared__ int h[NBUK];
    for (int i = threadIdx.x; i < NBUK; i += 256) h[i] = 0;
    __syncthreads();
    int c = blockIdx.x;
    int base = c * chunk_sz, end = min(base + chunk_sz, nnz);
    for (int e = base + threadIdx.x; e < end; e += 256)
        atomicAdd(&h[rows[e] >> 7], 1);
    __syncthreads();
    for (int b = threadIdx.x; b < NBUK; b += 256)
        cnt2[b * NCHK + c] = h[b];      // bucket-major: scan gives bucket-contiguous ranges
}

// ---------------------------------------------------------------- scan (3-pass, n = NSCAN)
__global__ __launch_bounds__(1024) void scan_block_sums(const int* __restrict__ cnt,
                                                        int* __restrict__ bsum, int n) {
    __shared__ int ws[16];
    int i = blockIdx.x * SCAN_CHUNK + threadIdx.x;
    int x = (i < n) ? cnt[i] : 0;
    #pragma unroll
    for (int d = 32; d >= 1; d >>= 1) x += __shfl_xor(x, d);
    int wid = threadIdx.x >> 6, lane = threadIdx.x & 63;
    if (lane == 0) ws[wid] = x;
    __syncthreads();
    if (threadIdx.x == 0) {
        int s = 0;
        #pragma unroll
        for (int k = 0; k < 16; ++k) s += ws[k];
        bsum[blockIdx.x] = s;
    }
}

__global__ void scan_small(const int* __restrict__ bsum, int* __restrict__ boff, int nb) {
    if (threadIdx.x == 0 && blockIdx.x == 0) {
        int acc = 0;
        for (int i = 0; i < nb; ++i) { boff[i] = acc; acc += bsum[i]; }
    }
}

__global__ __launch_bounds__(1024) void scan_chunks(const int* __restrict__ cnt,
                                                    const int* __restrict__ boff,
                                                    int* __restrict__ off, int n) {
    __shared__ int ws[16];
    int tid = threadIdx.x;
    int i = blockIdx.x * SCAN_CHUNK + tid;
    int x = (i < n) ? cnt[i] : 0;
    int v = x;
    #pragma unroll
    for (int d = 1; d < 64; d <<= 1) { int u = __shfl_up(v, d); if ((tid & 63) >= d) v += u; }
    int wid = tid >> 6, lane = tid & 63;
    if (lane == 63) ws[wid] = v;
    __syncthreads();
    if (wid == 0) {
        int s = (lane < 16) ? ws[lane] : 0;
        #pragma unroll
        for (int d = 1; d < 16; d <<= 1) { int u = __shfl_up(s, d); if (lane >= d) s += u; }
        if (lane < 16) ws[lane] = s;
    }
    __syncthreads();
    int woff = (wid == 0) ? 0 : ws[wid - 1];
    if (i < n) off[i] = boff[blockIdx.x] + woff + v - x;
}

// ---------------------------------------------------------------- partition into buckets (no global atomics)
__global__ __launch_bounds__(256) void partition_edges(
        const int* __restrict__ rows, const int* __restrict__ cols,
        const float* __restrict__ vals, const float* __restrict__ w3,
        const int* __restrict__ scanout, int2* __restrict__ tmp8,
        int nnz, int chunk_sz) {
    __shared__ int cur[NBUK];
    int c = blockIdx.x;
    for (int b = threadIdx.x; b < NBUK; b += 256) cur[b] = scanout[b * NCHK + c];
    __syncthreads();
    const float w0 = w3[0], w1 = w3[1], w2 = w3[2];
    int base = c * chunk_sz, end = min(base + chunk_sz, nnz);
    for (int e = base + threadIdx.x; e < end; e += 256) {
        int r = rows[e];
        float v = vals[e];
        float v2 = v * v;
        float comb = w0 * v + w1 * v2 + w2 * v2 * v2 * v2;
        int pos = atomicAdd(&cur[r >> 7], 1);
        tmp8[pos] = make_int2(((r & 127) << 17) | cols[e], __float_as_int(comb));
    }
}

// ---------------------------------------------------------------- in-bucket LDS counting sort -> 4B edges + row_off
__global__ __launch_bounds__(256) void bucket_sort(
        const int2* __restrict__ tmp8, const int* __restrict__ scanout,
        unsigned* __restrict__ edges4, int* __restrict__ row_off, int nnz) {
    __shared__ int hist[128], exc[129], cur[128];
    __shared__ unsigned st[BUKCAP];
    int b = blockIdx.x;
    int lo = scanout[b * NCHK];
    int hi = (b + 1 < NBUK) ? scanout[(b + 1) * NCHK] : nnz;
    int cnt = hi - lo;
    if (threadIdx.x < 128) hist[threadIdx.x] = 0;
    __syncthreads();
    for (int i = lo + threadIdx.x; i < hi; i += 256)
        atomicAdd(&hist[tmp8[i].x >> 17], 1);
    __syncthreads();
    if (threadIdx.x == 0) {
        int a = 0;
        for (int r = 0; r < 128; ++r) { exc[r] = a; a += hist[r]; }
        exc[128] = a;
    }
    __syncthreads();
    if (threadIdx.x < 128) {
        cur[threadIdx.x] = exc[threadIdx.x];
        int grow = b * 128 + threadIdx.x;
        if (grow <= NTOT) row_off[grow] = lo + exc[threadIdx.x];
    }
    __syncthreads();
    if (cnt <= BUKCAP) {
        for (int i = lo + threadIdx.x; i < hi; i += 256) {
            int2 t = tmp8[i];
            int rl = t.x >> 17;
            int p = atomicAdd(&cur[rl], 1);
            unsigned cb = (unsigned)f2bf(__int_as_float(t.y)) & 0x7FFFu;  // comb>0 -> sign 0
            st[p] = (cb << 17) | ((unsigned)t.x & 0x1FFFFu);
        }
        __syncthreads();
        for (int i = threadIdx.x; i < cnt; i += 256)
            edges4[lo + i] = st[i];                   // fully coalesced
    } else {
        // statistically unreachable fallback (cnt > BUKCAP)
        for (int i = lo + threadIdx.x; i < hi; i += 256) {
            int2 t = tmp8[i];
            int rl = t.x >> 17;
            int p = atomicAdd(&cur[rl], 1);
            unsigned cb = (unsigned)f2bf(__int_as_float(t.y)) & 0x7FFFu;
            edges4[lo + p] = (cb << 17) | ((unsigned)t.x & 0x1FFFFu);
        }
    }
}

// ---------------------------------------------------------------- SpMM (CSR, wave/row, 4-edge groups, 4B edges)
__global__ __launch_bounds__(256) void spmm_csr_h(const int* __restrict__ row_off,
                                                  const unsigned* __restrict__ edges4,
                                                  const unsigned short* __restrict__ Xh,
                                                  unsigned short* __restrict__ side_h) {
    int row = (blockIdx.x * blockDim.x + threadIdx.x) >> 6;
    if (row >= NTOT) return;
    int lane = threadIdx.x & 63;
    int g = lane >> 4;        // edge slot 0..3
    int q = lane & 15;        // dim slice: dims q*8 .. q*8+7
    int s = row_off[row], e = row_off[row + 1];

    float a[8];
    #pragma unroll
    for (int j = 0; j < 8; ++j) a[j] = 0.f;

    for (int i = s; i < e; i += 8) {
        int i0 = i + g, i1 = i + 4 + g;
        unsigned e0 = (i0 < e) ? edges4[i0] : 0u;
        unsigned e1 = (i1 < e) ? edges4[i1] : 0u;
        float v0 = bf2f((unsigned short)(e0 >> 17));
        float v1 = bf2f((unsigned short)(e1 >> 17));
        int4 x0 = *(const int4*)(Xh + (size_t)(e0 & 0x1FFFFu) * D + q * 8);
        int4 x1 = *(const int4*)(Xh + (size_t)(e1 & 0x1FFFFu) * D + q * 8);
        const unsigned short* p0 = (const unsigned short*)&x0;
        const unsigned short* p1 = (const unsigned short*)&x1;
        #pragma unroll
        for (int j = 0; j < 8; ++j)
            a[j] += v0 * bf2f(p0[j]) + v1 * bf2f(p1[j]);
    }
    #pragma unroll
    for (int j = 0; j < 8; ++j) {
        a[j] += __shfl_xor(a[j], 16);
        a[j] += __shfl_xor(a[j], 32);
    }
    if (g == 0) {
        unsigned short o[8];
        #pragma unroll
        for (int j = 0; j < 8; ++j) o[j] = f2bf(a[j]);
        *(int4*)(side_h + (size_t)row * D + q * 8) = *(int4*)o;
    }
}

// ---------------------------------------------------------------- fused MFMA layer GEMM
__global__ __launch_bounds__(256) void layer_gemm_mfma(
        const unsigned short* __restrict__ side_h,
        const unsigned short* __restrict__ ego_h,
        const unsigned short* __restrict__ Wp, int layer,
        const float* __restrict__ bgc, const float* __restrict__ bbi,
        unsigned short* __restrict__ ego_out_h, float* __restrict__ norms) {
    __shared__ unsigned short Sl[64 * D];
    __shared__ unsigned short Pl[64 * D];
    __shared__ float sqp[4][64];

    const int r0  = blockIdx.x * 64;
    const int tid = threadIdx.x;
    const int lane = tid & 63;
    const int wv   = tid >> 6;

    #pragma unroll
    for (int it = 0; it < 4; ++it) {
        int c = tid + it * 256;          // 1024 chunks of 16B
        int r = c >> 4;
        int q = c & 15;
        int row = r0 + r;
        int4 sv = make_int4(0, 0, 0, 0), ev = make_int4(0, 0, 0, 0);
        if (row < NTOT) {
            sv = *(const int4*)(side_h + (size_t)row * D + q * 8);
            ev = *(const int4*)(ego_h  + (size_t)row * D + q * 8);
        }
        int dst = (r * 256 + q * 16) ^ ((r & 7) << 4);
        *(int4*)((char*)Sl + dst) = sv;
        const unsigned short* sp = (const unsigned short*)&sv;
        const unsigned short* ep = (const unsigned short*)&ev;
        unsigned short pv[8];
        #pragma unroll
        for (int j = 0; j < 8; ++j) pv[j] = f2bf(bf2f(sp[j]) * bf2f(ep[j]));
        *(int4*)((char*)Pl + dst) = *(int4*)pv;
    }

    bfrag wg[4][2], wb[4][2];
    #pragma unroll
    for (int kt = 0; kt < 4; ++kt)
        #pragma unroll
        for (int n2 = 0; n2 < 2; ++n2) {
            int nt = wv * 2 + n2;
            size_t og = ((((size_t)(layer * 2 + 0) * 4 + kt) * 8 + nt) * 64 + lane) * 8;
            size_t ob = ((((size_t)(layer * 2 + 1) * 4 + kt) * 8 + nt) * 64 + lane) * 8;
            wg[kt][n2] = *(const bfrag*)(Wp + og);
            wb[kt][n2] = *(const bfrag*)(Wp + ob);
        }

    __syncthreads();

    f32x4 acc[4][2];
    #pragma unroll
    for (int m = 0; m < 4; ++m)
        #pragma unroll
        for (int n = 0; n < 2; ++n) acc[m][n] = (f32x4){0.f, 0.f, 0.f, 0.f};

    #pragma unroll
    for (int kt = 0; kt < 4; ++kt) {
        bfrag sf[4], pf[4];
        #pragma unroll
        for (int m = 0; m < 4; ++m) {
            int rowl = m * 16 + (lane & 15);
            int byte = (rowl * 256 + kt * 64 + (lane >> 4) * 16) ^ ((rowl & 7) << 4);
            sf[m] = *(const bfrag*)((const char*)Sl + byte);
            pf[m] = *(const bfrag*)((const char*)Pl + byte);
        }
        #pragma unroll
        for (int m = 0; m < 4; ++m)
            #pragma unroll
            for (int n = 0; n < 2; ++n) {
                acc[m][n] = __builtin_amdgcn_mfma_f32_16x16x32_bf16(sf[m], wg[kt][n], acc[m][n], 0, 0, 0);
                acc[m][n] = __builtin_amdgcn_mfma_f32_16x16x32_bf16(pf[m], wb[kt][n], acc[m][n], 0, 0, 0);
            }
    }

    float bsum[2];
    #pragma unroll
    for (int n = 0; n < 2; ++n) {
        int col = wv * 32 + n * 16 + (lane & 15);
        bsum[n] = bgc[col] + bbi[col];
    }

    float sq[4][4];
    #pragma unroll
    for (int m = 0; m < 4; ++m)
        #pragma unroll
        for (int r = 0; r < 4; ++r) sq[m][r] = 0.f;

    #pragma unroll
    for (int m = 0; m < 4; ++m) {
        int rowl = m * 16 + (lane >> 4) * 4;
        #pragma unroll
        for (int n = 0; n < 2; ++n) {
            int col = wv * 32 + n * 16 + (lane & 15);
            #pragma unroll
            for (int r = 0; r < 4; ++r) {
                float o = acc[m][n][r] + bsum[n];
                o = (o > 0.f) ? o : NEG_SLOPE * o;
                sq[m][r] += o * o;
                int row = r0 + rowl + r;
                if (row < NTOT)
                    ego_out_h[(size_t)row * D + col] = f2bf(o);
            }
        }
    }

    #pragma unroll
    for (int m = 0; m < 4; ++m)
        #pragma unroll
        for (int r = 0; r < 4; ++r) {
            float v = sq[m][r];
            #pragma unroll
            for (int off = 8; off >= 1; off >>= 1) v += __shfl_xor(v, off);
            if ((lane & 15) == 0) sqp[wv][m * 16 + (lane >> 4) * 4 + r] = v;
        }
    __syncthreads();
    if (tid < 64) {
        int row = r0 + tid;
        if (row < NTOT) {
            float s = sqp[0][tid] + sqp[1][tid] + sqp[2][tid] + sqp[3][tid];
            norms[row] = fmaxf(sqrtf(s), EPS_);
        }
    }
}

// ---------------------------------------------------------------- final gather (layer0 from raw f32 inputs)
__global__ void gather_out(const int* __restrict__ users,
                           const int* __restrict__ pos,
                           const int* __restrict__ neg,
                           const float* __restrict__ user_emb,
                           const float* __restrict__ item_emb1,
                           const float* __restrict__ item_emb2,
                           const float* __restrict__ feature,
                           const unsigned short* __restrict__ ego1h,
                           const unsigned short* __restrict__ ego2h,
                           const float* __restrict__ n1,
                           const float* __restrict__ n2,
                           float* __restrict__ out) {
    int t = blockIdx.x * blockDim.x + threadIdx.x;
    const int total = 3 * BATCH_ * 384;
    if (t >= total) return;
    int c = t % 384;
    int i = (t / 384) % BATCH_;
    int s = t / (384 * BATCH_);
    int idx  = (s == 0) ? users[i] : (s == 1 ? pos[i] : neg[i]);
    int node = (s == 0) ? idx : idx + N_USER;
    float val;
    if (c < 128) {
        if (s == 0)
            val = (c < 64) ? user_emb[(size_t)idx * 64 + c]
                           : feature[(size_t)idx * 64 + (c - 64)];
        else
            val = (c < 64) ? item_emb1[(size_t)idx * 64 + c]
                           : item_emb2[(size_t)idx * 64 + (c - 64)];
    } else if (c < 256) {
        val = bf2f(ego1h[(size_t)node * D + (c - 128)]) / n1[node];
    } else {
        val = bf2f(ego2h[(size_t)node * D + (c - 256)]) / n2[node];
    }
    out[t] = val;
}

// ---------------------------------------------------------------- launch
extern "C" void kernel_launch(void* const* d_in, const int* in_sizes, int n_in,
                              void* d_out, int out_size, void* d_ws, size_t ws_size,
                              hipStream_t stream) {
    const int*   users     = (const int*)d_in[0];
    const int*   pos_items = (const int*)d_in[1];
    const int*   neg_items = (const int*)d_in[2];
    const float* user_emb  = (const float*)d_in[3];
    const float* item_emb1 = (const float*)d_in[4];
    const float* item_emb2 = (const float*)d_in[5];
    const float* feature   = (const float*)d_in[6];
    const float* w3        = (const float*)d_in[7];
    const float* W_gc      = (const float*)d_in[8];
    const float* b_gc      = (const float*)d_in[9];
    const float* W_bi      = (const float*)d_in[10];
    const float* b_bi      = (const float*)d_in[11];
    const int*   adj_rows  = (const int*)d_in[12];
    const int*   adj_cols  = (const int*)d_in[13];
    const float* adj_vals  = (const float*)d_in[14];
    const int nnz = in_sizes[14];

    const size_t nd = (size_t)NTOT * D;
    const int NB2 = (NSCAN + SCAN_CHUNK - 1) / SCAN_CHUNK;   // 98

    char* p = (char*)d_ws;
    float* n1    = (float*)p;                 p += NTOT * 4;
    float* n2    = (float*)p;                 p += NTOT * 4;
    unsigned short* ego0h  = (unsigned short*)p; p += nd * 2;
    unsigned short* ego1h  = (unsigned short*)p; p += nd * 2;
    unsigned short* ego2h  = (unsigned short*)p; p += nd * 2;
    unsigned short* side_h = (unsigned short*)p; p += nd * 2;
    unsigned short* Wp     = (unsigned short*)p; p += 8192 * 8 * 2;
    int*  row_off = (int*)p;                  p += (NTOT + 4) * 4;
    int*  cnt2    = (int*)p;                  p += (size_t)NSCAN * 4;
    int*  scanout = (int*)p;                  p += (size_t)NSCAN * 4;
    int*  bsum    = (int*)p;                  p += 128 * 4;
    int*  boff    = (int*)p;                  p += 128 * 4;
    int2* tmp8    = (int2*)p;                 p += (size_t)nnz * 8;
    unsigned* edges4 = (unsigned*)p;          p += (size_t)nnz * 4;

    float* out = (float*)d_out;

    {
        int total = NTOT * (D / 4);
        assemble_ego0<<<(total + 255) / 256, 256, 0, stream>>>(
            user_emb, item_emb1, item_emb2, feature, ego0h);
    }
    pack_w<<<8192 / 256, 256, 0, stream>>>(W_gc, W_bi, Wp);

    // ---- CSR build: hist -> scan -> partition -> in-bucket sort
    int chunk_sz = (nnz + NCHK - 1) / NCHK;
    hist_buckets<<<NCHK, 256, 0, stream>>>(adj_rows, cnt2, nnz, chunk_sz);
    scan_block_sums<<<NB2, SCAN_CHUNK, 0, stream>>>(cnt2, bsum, NSCAN);
    scan_small<<<1, 64, 0, stream>>>(bsum, boff, NB2);
    scan_chunks<<<NB2, SCAN_CHUNK, 0, stream>>>(cnt2, boff, scanout, NSCAN);
    partition_edges<<<NCHK, 256, 0, stream>>>(adj_rows, adj_cols, adj_vals, w3,
                                              scanout, tmp8, nnz, chunk_sz);
    bucket_sort<<<NBUK, 256, 0, stream>>>(tmp8, scanout, edges4, row_off, nnz);

    for (int k = 0; k < 2; ++k) {
        const unsigned short* Xh = (k == 0) ? ego0h : ego1h;
        unsigned short* egoNh    = (k == 0) ? ego1h : ego2h;
        float* nrm               = (k == 0) ? n1 : n2;

        spmm_csr_h<<<(NTOT + 3) / 4, 256, 0, stream>>>(row_off, edges4, Xh, side_h);
        layer_gemm_mfma<<<(NTOT + 63) / 64, 256, 0, stream>>>(
            side_h, Xh, Wp, k,
            b_gc + (size_t)k * D, b_bi + (size_t)k * D,
            egoNh, nrm);
    }

    {
        int total = 3 * BATCH_ * 384;
        gather_out<<<(total + 255) / 256, 256, 0, stream>>>(
            users, pos_items, neg_items,
            user_emb, item_emb1, item_emb2, feature,
            ego1h, ego2h, n1, n2, out);
    }
}

// Round 6
// 380.138 us; speedup vs baseline: 8.1651x; 1.1682x over previous
//
#include <hip/hip_runtime.h>
#include <math.h>

#define N_USER 50000
#define N_ITEM 50000
#define NTOT   100000
#define D      128
#define BATCH_ 4096
#define NEG_SLOPE 0.2f
#define EPS_ 1e-12f
#define SCAN_CHUNK 1024
#define NBUK 782            // buckets of 128 rows
#define NCHK 256            // edge chunks for partition
#define NSCAN (NBUK * NCHK) // 200192
#define BUKCAP 12288        // max edges/bucket for LDS sort (mean 4092)

typedef __attribute__((ext_vector_type(8))) short bfrag;
typedef __attribute__((ext_vector_type(4))) float f32x4;

static __device__ __forceinline__ float bf2f(unsigned short h) {
    return __uint_as_float(((unsigned)h) << 16);
}
static __device__ __forceinline__ unsigned short f2bf(float f) {
    unsigned u = __float_as_uint(f);
    u += 0x7fffu + ((u >> 16) & 1u);   // round-to-nearest-even
    return (unsigned short)(u >> 16);
}

// ---------------------------------------------------------------- ego0 assembly (bf16 only)
__global__ void assemble_ego0(const float* __restrict__ user_emb,
                              const float* __restrict__ item_emb1,
                              const float* __restrict__ item_emb2,
                              const float* __restrict__ feature,
                              unsigned short* __restrict__ ego0h) {
    int t = blockIdx.x * blockDim.x + threadIdx.x;   // float4 slot
    const int total = NTOT * (D / 4);
    if (t >= total) return;
    int row = t >> 5;
    int q   = t & 31;
    int d0  = q * 4;
    const float* src;
    if (d0 < 64) {
        src = (row < N_USER) ? user_emb  + (size_t)row * 64 + d0
                             : item_emb1 + (size_t)(row - N_USER) * 64 + d0;
    } else {
        src = (row < N_USER) ? feature   + (size_t)row * 64 + (d0 - 64)
                             : item_emb2 + (size_t)(row - N_USER) * 64 + (d0 - 64);
    }
    float4 v = *(const float4*)src;
    ushort4 h;
    h.x = f2bf(v.x); h.y = f2bf(v.y); h.z = f2bf(v.z); h.w = f2bf(v.w);
    *(ushort4*)(ego0h + (size_t)row * D + d0) = h;
}

// ---------------------------------------------------------------- W pre-pack (bf16, frag-major)
__global__ void pack_w(const float* __restrict__ W_gc, const float* __restrict__ W_bi,
                       unsigned short* __restrict__ Wp) {
    int t = blockIdx.x * blockDim.x + threadIdx.x;
    if (t >= 8192) return;
    int lane  = t & 63;
    int nt    = (t >> 6) & 7;
    int kt    = (t >> 9) & 3;
    int mat   = (t >> 11) & 1;
    int layer = (t >> 12) & 1;
    const float* W = (mat ? W_bi : W_gc) + (size_t)layer * D * D;
    int n = nt * 16 + (lane & 15);
    int kbase = kt * 32 + (lane >> 4) * 8;
    unsigned short o8[8];
    #pragma unroll
    for (int e = 0; e < 8; ++e) o8[e] = f2bf(W[(size_t)(kbase + e) * D + n]);
    *(int4*)(Wp + (size_t)t * 8) = *(int4*)o8;
}

// ---------------------------------------------------------------- bucket histogram (chunk-blocks, 1024 thr)
__global__ __launch_bounds__(1024) void hist_buckets(const int* __restrict__ rows,
                                                     int* __restrict__ cnt2,
                                                     int nnz, int chunk_sz) {
    __shared__ int h[NBUK];
    for (int i = threadIdx.x; i < NBUK; i += 1024) h[i] = 0;
    __syncthreads();
    int c = blockIdx.x;
    int base = c * chunk_sz, end = min(base + chunk_sz, nnz);
    for (int e = base + threadIdx.x; e < end; e += 1024)
        atomicAdd(&h[rows[e] >> 7], 1);
    __syncthreads();
    for (int b = threadIdx.x; b < NBUK; b += 1024)
        cnt2[b * NCHK + c] = h[b];      // bucket-major: scan gives bucket-contiguous ranges
}

// ---------------------------------------------------------------- scan (3-pass, n = NSCAN)
__global__ __launch_bounds__(1024) void scan_block_sums(const int* __restrict__ cnt,
                                                        int* __restrict__ bsum, int n) {
    __shared__ int ws[16];
    int i = blockIdx.x * SCAN_CHUNK + threadIdx.x;
    int x = (i < n) ? cnt[i] : 0;
    #pragma unroll
    for (int d = 32; d >= 1; d >>= 1) x += __shfl_xor(x, d);
    int wid = threadIdx.x >> 6, lane = threadIdx.x & 63;
    if (lane == 0) ws[wid] = x;
    __syncthreads();
    if (threadIdx.x == 0) {
        int s = 0;
        #pragma unroll
        for (int k = 0; k < 16; ++k) s += ws[k];
        bsum[blockIdx.x] = s;
    }
}

__global__ void scan_small(const int* __restrict__ bsum, int* __restrict__ boff, int nb) {
    if (threadIdx.x == 0 && blockIdx.x == 0) {
        int acc = 0;
        for (int i = 0; i < nb; ++i) { boff[i] = acc; acc += bsum[i]; }
    }
}

__global__ __launch_bounds__(1024) void scan_chunks(const int* __restrict__ cnt,
                                                    const int* __restrict__ boff,
                                                    int* __restrict__ off, int n) {
    __shared__ int ws[16];
    int tid = threadIdx.x;
    int i = blockIdx.x * SCAN_CHUNK + tid;
    int x = (i < n) ? cnt[i] : 0;
    int v = x;
    #pragma unroll
    for (int d = 1; d < 64; d <<= 1) { int u = __shfl_up(v, d); if ((tid & 63) >= d) v += u; }
    int wid = tid >> 6, lane = tid & 63;
    if (lane == 63) ws[wid] = v;
    __syncthreads();
    if (wid == 0) {
        int s = (lane < 16) ? ws[lane] : 0;
        #pragma unroll
        for (int d = 1; d < 16; d <<= 1) { int u = __shfl_up(s, d); if (lane >= d) s += u; }
        if (lane < 16) ws[lane] = s;
    }
    __syncthreads();
    int woff = (wid == 0) ? 0 : ws[wid - 1];
    if (i < n) off[i] = boff[blockIdx.x] + woff + v - x;
}

// ---------------------------------------------------------------- partition into buckets (no global atomics, 1024 thr)
__global__ __launch_bounds__(1024) void partition_edges(
        const int* __restrict__ rows, const int* __restrict__ cols,
        const float* __restrict__ vals, const float* __restrict__ w3,
        const int* __restrict__ scanout, int2* __restrict__ tmp8,
        int nnz, int chunk_sz) {
    __shared__ int cur[NBUK];
    int c = blockIdx.x;
    for (int b = threadIdx.x; b < NBUK; b += 1024) cur[b] = scanout[b * NCHK + c];
    __syncthreads();
    const float w0 = w3[0], w1 = w3[1], w2 = w3[2];
    int base = c * chunk_sz, end = min(base + chunk_sz, nnz);
    for (int e = base + threadIdx.x; e < end; e += 1024) {
        int r = rows[e];
        float v = vals[e];
        float v2 = v * v;
        float comb = w0 * v + w1 * v2 + w2 * v2 * v2 * v2;
        int pos = atomicAdd(&cur[r >> 7], 1);
        tmp8[pos] = make_int2(((r & 127) << 17) | cols[e], __float_as_int(comb));
    }
}

// ---------------------------------------------------------------- in-bucket LDS counting sort -> 4B edges + row_off
__global__ __launch_bounds__(256) void bucket_sort(
        const int2* __restrict__ tmp8, const int* __restrict__ scanout,
        unsigned* __restrict__ edges4, int* __restrict__ row_off, int nnz) {
    __shared__ int hist[128], exc[129], cur[128];
    __shared__ unsigned st[BUKCAP];
    int b = blockIdx.x;
    int lo = scanout[b * NCHK];
    int hi = (b + 1 < NBUK) ? scanout[(b + 1) * NCHK] : nnz;
    int cnt = hi - lo;
    if (threadIdx.x < 128) hist[threadIdx.x] = 0;
    __syncthreads();
    for (int i = lo + threadIdx.x; i < hi; i += 256)
        atomicAdd(&hist[tmp8[i].x >> 17], 1);
    __syncthreads();
    if (threadIdx.x == 0) {
        int a = 0;
        for (int r = 0; r < 128; ++r) { exc[r] = a; a += hist[r]; }
        exc[128] = a;
    }
    __syncthreads();
    if (threadIdx.x < 128) {
        cur[threadIdx.x] = exc[threadIdx.x];
        int grow = b * 128 + threadIdx.x;
        if (grow <= NTOT) row_off[grow] = lo + exc[threadIdx.x];
    }
    __syncthreads();
    if (cnt <= BUKCAP) {
        for (int i = lo + threadIdx.x; i < hi; i += 256) {
            int2 t = tmp8[i];
            int rl = t.x >> 17;
            int p = atomicAdd(&cur[rl], 1);
            unsigned cb = (unsigned)f2bf(__int_as_float(t.y)) & 0x7FFFu;  // comb>0 -> sign 0
            st[p] = (cb << 17) | ((unsigned)t.x & 0x1FFFFu);
        }
        __syncthreads();
        for (int i = threadIdx.x; i < cnt; i += 256)
            edges4[lo + i] = st[i];                   // fully coalesced
    } else {
        // statistically unreachable fallback (cnt > BUKCAP)
        for (int i = lo + threadIdx.x; i < hi; i += 256) {
            int2 t = tmp8[i];
            int rl = t.x >> 17;
            int p = atomicAdd(&cur[rl], 1);
            unsigned cb = (unsigned)f2bf(__int_as_float(t.y)) & 0x7FFFu;
            edges4[lo + p] = (cb << 17) | ((unsigned)t.x & 0x1FFFFu);
        }
    }
}

// ---------------------------------------------------------------- SpMM (CSR, wave/row, 4-edge groups, 4B edges)
__global__ __launch_bounds__(256) void spmm_csr_h(const int* __restrict__ row_off,
                                                  const unsigned* __restrict__ edges4,
                                                  const unsigned short* __restrict__ Xh,
                                                  unsigned short* __restrict__ side_h) {
    int row = (blockIdx.x * blockDim.x + threadIdx.x) >> 6;
    if (row >= NTOT) return;
    int lane = threadIdx.x & 63;
    int g = lane >> 4;        // edge slot 0..3
    int q = lane & 15;        // dim slice: dims q*8 .. q*8+7
    int s = row_off[row], e = row_off[row + 1];

    float a[8];
    #pragma unroll
    for (int j = 0; j < 8; ++j) a[j] = 0.f;

    for (int i = s; i < e; i += 8) {
        int i0 = i + g, i1 = i + 4 + g;
        unsigned e0 = (i0 < e) ? edges4[i0] : 0u;
        unsigned e1 = (i1 < e) ? edges4[i1] : 0u;
        float v0 = bf2f((unsigned short)(e0 >> 17));
        float v1 = bf2f((unsigned short)(e1 >> 17));
        int4 x0 = *(const int4*)(Xh + (size_t)(e0 & 0x1FFFFu) * D + q * 8);
        int4 x1 = *(const int4*)(Xh + (size_t)(e1 & 0x1FFFFu) * D + q * 8);
        const unsigned short* p0 = (const unsigned short*)&x0;
        const unsigned short* p1 = (const unsigned short*)&x1;
        #pragma unroll
        for (int j = 0; j < 8; ++j)
            a[j] += v0 * bf2f(p0[j]) + v1 * bf2f(p1[j]);
    }
    #pragma unroll
    for (int j = 0; j < 8; ++j) {
        a[j] += __shfl_xor(a[j], 16);
        a[j] += __shfl_xor(a[j], 32);
    }
    if (g == 0) {
        unsigned short o[8];
        #pragma unroll
        for (int j = 0; j < 8; ++j) o[j] = f2bf(a[j]);
        *(int4*)(side_h + (size_t)row * D + q * 8) = *(int4*)o;
    }
}

// ---------------------------------------------------------------- fused MFMA layer GEMM
__global__ __launch_bounds__(256) void layer_gemm_mfma(
        const unsigned short* __restrict__ side_h,
        const unsigned short* __restrict__ ego_h,
        const unsigned short* __restrict__ Wp, int layer,
        const float* __restrict__ bgc, const float* __restrict__ bbi,
        unsigned short* __restrict__ ego_out_h, float* __restrict__ norms) {
    __shared__ unsigned short Sl[64 * D];
    __shared__ unsigned short Pl[64 * D];
    __shared__ float sqp[4][64];

    const int r0  = blockIdx.x * 64;
    const int tid = threadIdx.x;
    const int lane = tid & 63;
    const int wv   = tid >> 6;

    #pragma unroll
    for (int it = 0; it < 4; ++it) {
        int c = tid + it * 256;          // 1024 chunks of 16B
        int r = c >> 4;
        int q = c & 15;
        int row = r0 + r;
        int4 sv = make_int4(0, 0, 0, 0), ev = make_int4(0, 0, 0, 0);
        if (row < NTOT) {
            sv = *(const int4*)(side_h + (size_t)row * D + q * 8);
            ev = *(const int4*)(ego_h  + (size_t)row * D + q * 8);
        }
        int dst = (r * 256 + q * 16) ^ ((r & 7) << 4);
        *(int4*)((char*)Sl + dst) = sv;
        const unsigned short* sp = (const unsigned short*)&sv;
        const unsigned short* ep = (const unsigned short*)&ev;
        unsigned short pv[8];
        #pragma unroll
        for (int j = 0; j < 8; ++j) pv[j] = f2bf(bf2f(sp[j]) * bf2f(ep[j]));
        *(int4*)((char*)Pl + dst) = *(int4*)pv;
    }

    bfrag wg[4][2], wb[4][2];
    #pragma unroll
    for (int kt = 0; kt < 4; ++kt)
        #pragma unroll
        for (int n2 = 0; n2 < 2; ++n2) {
            int nt = wv * 2 + n2;
            size_t og = ((((size_t)(layer * 2 + 0) * 4 + kt) * 8 + nt) * 64 + lane) * 8;
            size_t ob = ((((size_t)(layer * 2 + 1) * 4 + kt) * 8 + nt) * 64 + lane) * 8;
            wg[kt][n2] = *(const bfrag*)(Wp + og);
            wb[kt][n2] = *(const bfrag*)(Wp + ob);
        }

    __syncthreads();

    f32x4 acc[4][2];
    #pragma unroll
    for (int m = 0; m < 4; ++m)
        #pragma unroll
        for (int n = 0; n < 2; ++n) acc[m][n] = (f32x4){0.f, 0.f, 0.f, 0.f};

    #pragma unroll
    for (int kt = 0; kt < 4; ++kt) {
        bfrag sf[4], pf[4];
        #pragma unroll
        for (int m = 0; m < 4; ++m) {
            int rowl = m * 16 + (lane & 15);
            int byte = (rowl * 256 + kt * 64 + (lane >> 4) * 16) ^ ((rowl & 7) << 4);
            sf[m] = *(const bfrag*)((const char*)Sl + byte);
            pf[m] = *(const bfrag*)((const char*)Pl + byte);
        }
        #pragma unroll
        for (int m = 0; m < 4; ++m)
            #pragma unroll
            for (int n = 0; n < 2; ++n) {
                acc[m][n] = __builtin_amdgcn_mfma_f32_16x16x32_bf16(sf[m], wg[kt][n], acc[m][n], 0, 0, 0);
                acc[m][n] = __builtin_amdgcn_mfma_f32_16x16x32_bf16(pf[m], wb[kt][n], acc[m][n], 0, 0, 0);
            }
    }

    float bsum[2];
    #pragma unroll
    for (int n = 0; n < 2; ++n) {
        int col = wv * 32 + n * 16 + (lane & 15);
        bsum[n] = bgc[col] + bbi[col];
    }

    float sq[4][4];
    #pragma unroll
    for (int m = 0; m < 4; ++m)
        #pragma unroll
        for (int r = 0; r < 4; ++r) sq[m][r] = 0.f;

    #pragma unroll
    for (int m = 0; m < 4; ++m) {
        int rowl = m * 16 + (lane >> 4) * 4;
        #pragma unroll
        for (int n = 0; n < 2; ++n) {
            int col = wv * 32 + n * 16 + (lane & 15);
            #pragma unroll
            for (int r = 0; r < 4; ++r) {
                float o = acc[m][n][r] + bsum[n];
                o = (o > 0.f) ? o : NEG_SLOPE * o;
                sq[m][r] += o * o;
                int row = r0 + rowl + r;
                if (row < NTOT)
                    ego_out_h[(size_t)row * D + col] = f2bf(o);
            }
        }
    }

    #pragma unroll
    for (int m = 0; m < 4; ++m)
        #pragma unroll
        for (int r = 0; r < 4; ++r) {
            float v = sq[m][r];
            #pragma unroll
            for (int off = 8; off >= 1; off >>= 1) v += __shfl_xor(v, off);
            if ((lane & 15) == 0) sqp[wv][m * 16 + (lane >> 4) * 4 + r] = v;
        }
    __syncthreads();
    if (tid < 64) {
        int row = r0 + tid;
        if (row < NTOT) {
            float s = sqp[0][tid] + sqp[1][tid] + sqp[2][tid] + sqp[3][tid];
            norms[row] = fmaxf(sqrtf(s), EPS_);
        }
    }
}

// ---------------------------------------------------------------- final gather (layer0 from raw f32 inputs)
__global__ void gather_out(const int* __restrict__ users,
                           const int* __restrict__ pos,
                           const int* __restrict__ neg,
                           const float* __restrict__ user_emb,
                           const float* __restrict__ item_emb1,
                           const float* __restrict__ item_emb2,
                           const float* __restrict__ feature,
                           const unsigned short* __restrict__ ego1h,
                           const unsigned short* __restrict__ ego2h,
                           const float* __restrict__ n1,
                           const float* __restrict__ n2,
                           float* __restrict__ out) {
    int t = blockIdx.x * blockDim.x + threadIdx.x;
    const int total = 3 * BATCH_ * 384;
    if (t >= total) return;
    int c = t % 384;
    int i = (t / 384) % BATCH_;
    int s = t / (384 * BATCH_);
    int idx  = (s == 0) ? users[i] : (s == 1 ? pos[i] : neg[i]);
    int node = (s == 0) ? idx : idx + N_USER;
    float val;
    if (c < 128) {
        if (s == 0)
            val = (c < 64) ? user_emb[(size_t)idx * 64 + c]
                           : feature[(size_t)idx * 64 + (c - 64)];
        else
            val = (c < 64) ? item_emb1[(size_t)idx * 64 + c]
                           : item_emb2[(size_t)idx * 64 + (c - 64)];
    } else if (c < 256) {
        val = bf2f(ego1h[(size_t)node * D + (c - 128)]) / n1[node];
    } else {
        val = bf2f(ego2h[(size_t)node * D + (c - 256)]) / n2[node];
    }
    out[t] = val;
}

// ---------------------------------------------------------------- launch
extern "C" void kernel_launch(void* const* d_in, const int* in_sizes, int n_in,
                              void* d_out, int out_size, void* d_ws, size_t ws_size,
                              hipStream_t stream) {
    const int*   users     = (const int*)d_in[0];
    const int*   pos_items = (const int*)d_in[1];
    const int*   neg_items = (const int*)d_in[2];
    const float* user_emb  = (const float*)d_in[3];
    const float* item_emb1 = (const float*)d_in[4];
    const float* item_emb2 = (const float*)d_in[5];
    const float* feature   = (const float*)d_in[6];
    const float* w3        = (const float*)d_in[7];
    const float* W_gc      = (const float*)d_in[8];
    const float* b_gc      = (const float*)d_in[9];
    const float* W_bi      = (const float*)d_in[10];
    const float* b_bi      = (const float*)d_in[11];
    const int*   adj_rows  = (const int*)d_in[12];
    const int*   adj_cols  = (const int*)d_in[13];
    const float* adj_vals  = (const float*)d_in[14];
    const int nnz = in_sizes[14];

    const size_t nd = (size_t)NTOT * D;
    const int NB2 = (NSCAN + SCAN_CHUNK - 1) / SCAN_CHUNK;   // 196

    char* p = (char*)d_ws;
    float* n1    = (float*)p;                 p += NTOT * 4;
    float* n2    = (float*)p;                 p += NTOT * 4;
    unsigned short* ego0h  = (unsigned short*)p; p += nd * 2;
    unsigned short* ego1h  = (unsigned short*)p; p += nd * 2;
    unsigned short* ego2h  = (unsigned short*)p; p += nd * 2;
    unsigned short* side_h = (unsigned short*)p; p += nd * 2;
    unsigned short* Wp     = (unsigned short*)p; p += 8192 * 8 * 2;
    int*  row_off = (int*)p;                  p += (NTOT + 4) * 4;
    int*  cnt2    = (int*)p;                  p += (size_t)NSCAN * 4;
    int*  scanout = (int*)p;                  p += (size_t)NSCAN * 4;
    int*  bsum    = (int*)p;                  p += 256 * 4;
    int*  boff    = (int*)p;                  p += 256 * 4;
    int2* tmp8    = (int2*)p;                 p += (size_t)nnz * 8;
    unsigned* edges4 = (unsigned*)p;          p += (size_t)nnz * 4;

    float* out = (float*)d_out;

    {
        int total = NTOT * (D / 4);
        assemble_ego0<<<(total + 255) / 256, 256, 0, stream>>>(
            user_emb, item_emb1, item_emb2, feature, ego0h);
    }
    pack_w<<<8192 / 256, 256, 0, stream>>>(W_gc, W_bi, Wp);

    // ---- CSR build: hist -> scan -> partition -> in-bucket sort
    int chunk_sz = (nnz + NCHK - 1) / NCHK;
    hist_buckets<<<NCHK, 1024, 0, stream>>>(adj_rows, cnt2, nnz, chunk_sz);
    scan_block_sums<<<NB2, SCAN_CHUNK, 0, stream>>>(cnt2, bsum, NSCAN);
    scan_small<<<1, 64, 0, stream>>>(bsum, boff, NB2);
    scan_chunks<<<NB2, SCAN_CHUNK, 0, stream>>>(cnt2, boff, scanout, NSCAN);
    partition_edges<<<NCHK, 1024, 0, stream>>>(adj_rows, adj_cols, adj_vals, w3,
                                               scanout, tmp8, nnz, chunk_sz);
    bucket_sort<<<NBUK, 256, 0, stream>>>(tmp8, scanout, edges4, row_off, nnz);

    for (int k = 0; k < 2; ++k) {
        const unsigned short* Xh = (k == 0) ? ego0h : ego1h;
        unsigned short* egoNh    = (k == 0) ? ego1h : ego2h;
        float* nrm               = (k == 0) ? n1 : n2;

        spmm_csr_h<<<(NTOT + 3) / 4, 256, 0, stream>>>(row_off, edges4, Xh, side_h);
        layer_gemm_mfma<<<(NTOT + 63) / 64, 256, 0, stream>>>(
            side_h, Xh, Wp, k,
            b_gc + (size_t)k * D, b_bi + (size_t)k * D,
            egoNh, nrm);
    }

    {
        int total = 3 * BATCH_ * 384;
        gather_out<<<(total + 255) / 256, 256, 0, stream>>>(
            users, pos_items, neg_items,
            user_emb, item_emb1, item_emb2, feature,
            ego1h, ego2h, n1, n2, out);
    }
}